// Round 8
// baseline (220.069 us; speedup 1.0000x reference)
//
#include <hip/hip_runtime.h>
#include <math.h>

// ---------- problem constants ----------
// B=16, F=256, C=64, H=64, W=64, N_E=512. Inputs fp32, outputs fp32.
// tokens: rows r=(b*64+c)*64+h of 64 w-values; 65536 tokens total.
// bf16-split MFMA GEMM + bf16-split MFMA VQ; near-ties re-resolved in fp64.
// R8: R6 config (best, 181.7) with prep fused into K1 as ticket-spin blocks.

#define CAP    2048
#define MARGIN 4e-3f

// ---------- workspace layout (float offsets) ----------
#define WS_WHI  0        // [16384 ushort] W' hi bf16, A-frag order
#define WS_WLO  8192     // [16384 ushort] W' lo bf16
#define WS_BP   16384    // [64]
#define WS_EN   16448    // [512]
#define WS_E2   16960    // [512]
#define WS_ACC  17472    // [8]
#define WS_CNT  17480    // [8]
#define WS_WL   17488    // [2048]
#define WS_EFT  19536    // [64*512] fp32 emb^T
#define WS_WD   52304    // [16384 dbl]
#define WS_BPD  85072    // [64 dbl]
#define WS_EHI  85200    // [32768 ushort] emb hi bf16, XOR-swizzled granules
#define WS_ELO  101584   // [32768 ushort] emb lo bf16, swizzled
#define WS_PART 117968   // [2048 dbl] bn partials (1024 blocks x {s,q})
#define WS_SV   122064   // [512] cb-stats per-row variance partials
#define WS_SM   122576   // [512] cb-stats per-row 2nd-min partials
#define WS_TKT  123088   // [4] BN-done ticket (memset to 0 pre-launch)

typedef __attribute__((ext_vector_type(8))) __bf16 bf16v8;
typedef __attribute__((ext_vector_type(2))) __bf16 bf16v2;
typedef __attribute__((ext_vector_type(4))) float  f32v4;
typedef __attribute__((ext_vector_type(4))) unsigned u32v4;

__device__ __forceinline__ unsigned short f2bf(float f) {
    __bf16 h = (__bf16)f;
    return __builtin_bit_cast(unsigned short, h);
}
__device__ __forceinline__ float bf2f(unsigned short h) {
    union { unsigned u; float f; } v; v.u = ((unsigned)h) << 16; return v.f;
}
__device__ __forceinline__ unsigned pack_bf2(float a, float b) {
    bf16v2 v = { (__bf16)a, (__bf16)b };
    return __builtin_bit_cast(unsigned, v);
}
__device__ __forceinline__ float bfhi(float a) {
    return (float)(__bf16)a;
}
__device__ __forceinline__ void load_lds16(const float* g, unsigned* l) {
    __builtin_amdgcn_global_load_lds((const __attribute__((address_space(1))) void*)g,
                                     (__attribute__((address_space(3))) void*)l, 16, 0, 0);
}

// ============================================================
// K1 (fused): blocks 0..1023: BN partials (+ticket). 1024..1087: emb prep.
// 1088..1599: cb angular stats. 1600..1663: W' fold (spin on ticket==1024).
// 1664: bias + zero accs (spin). Prep overlaps the cb-stats tail.
// ============================================================
__global__ __launch_bounds__(256) void bn_stats_prep(
    const float* __restrict__ x, double* __restrict__ part,
    const float* __restrict__ emb,
    const float* __restrict__ w1, const float* __restrict__ w2,
    const float* __restrict__ b1, const float* __restrict__ b2,
    const float* __restrict__ gamma, const float* __restrict__ beta,
    float* __restrict__ eft, float* __restrict__ en, float* __restrict__ e2,
    unsigned short* __restrict__ ehi, unsigned short* __restrict__ elo,
    float* __restrict__ sv, float* __restrict__ sm,
    unsigned short* __restrict__ whi, unsigned short* __restrict__ wlo,
    double* __restrict__ Wd, double* __restrict__ bpd, float* __restrict__ bp,
    float* __restrict__ accs, int* __restrict__ cnt, int* __restrict__ tkt)
{
    const int t = threadIdx.x;

    if (blockIdx.x < 1024) {
        // ---- BN partial sums ----
        const int f = blockIdx.x >> 2, ch = blockIdx.x & 3;
        double s0 = 0.0, s1 = 0.0, q0 = 0.0, q1 = 0.0, q2 = 0.0, q3 = 0.0;
        #pragma unroll
        for (int bb = 0; bb < 4; ++bb) {
            const int b = ch * 4 + bb;
            const float4* p = (const float4*)(x + ((size_t)(b * 256 + f) << 12));
            #pragma unroll
            for (int ii = 0; ii < 4; ++ii) {
                float4 u = p[t + ii * 256];
                double dx = u.x, dy = u.y, dz = u.z, dw = u.w;
                s0 += dx + dy; s1 += dz + dw;
                q0 = fma(dx, dx, q0); q1 = fma(dy, dy, q1);
                q2 = fma(dz, dz, q2); q3 = fma(dw, dw, q3);
            }
        }
        double s = s0 + s1, q = (q0 + q1) + (q2 + q3);
        #pragma unroll
        for (int off = 32; off; off >>= 1) { s += __shfl_xor(s, off, 64); q += __shfl_xor(q, off, 64); }
        __shared__ double sh[8];
        const int wv = t >> 6;
        if ((t & 63) == 0) { sh[wv * 2] = s; sh[wv * 2 + 1] = q; }
        __syncthreads();
        if (t == 0) {
            part[blockIdx.x * 2]     = (sh[0] + sh[2]) + (sh[4] + sh[6]);
            part[blockIdx.x * 2 + 1] = (sh[1] + sh[3]) + (sh[5] + sh[7]);
            __threadfence();
            atomicAdd(tkt, 1);
        }
    } else if (blockIdx.x < 1088) {
        // ---- embedding prep: 8 rows per block ----
        const int blk = blockIdx.x - 1024;
        const int lane = t & 63, wv = t >> 6;
        #pragma unroll
        for (int rr = 0; rr < 2; ++rr) {
            int n = blk * 8 + rr * 4 + wv;
            float v = emb[n * 64 + lane];
            eft[lane * 512 + n] = v;
            unsigned short hb = f2bf(v);
            unsigned short lb = f2bf(v - bf2f(hb));
            int pos = (lane >> 3) ^ (n & 7);          // XOR-swizzled granule
            ehi[n * 64 + pos * 8 + (lane & 7)] = hb;
            elo[n * 64 + pos * 8 + (lane & 7)] = lb;
            float qq = v * v;
            #pragma unroll
            for (int off = 32; off; off >>= 1) qq += __shfl_xor(qq, off, 64);
            if (lane == 0) { e2[n] = qq; en[n] = sqrtf(qq); }
        }
    } else if (blockIdx.x < 1600) {
        // ---- codebook angular stats for row i (reads emb directly) ----
        const int i = blockIdx.x - 1088;
        const int lane = t & 63, wv = t >> 6;
        __shared__ float ei_sh[64];
        __shared__ float ang[512];
        if (t < 64) ei_sh[t] = emb[(i << 6) + t];
        __syncthreads();
        float ni0 = 0.f, ni1 = 0.f, ni2 = 0.f, ni3 = 0.f;
        #pragma unroll
        for (int k = 0; k < 64; k += 4) {
            ni0 = fmaf(ei_sh[k + 0], ei_sh[k + 0], ni0);
            ni1 = fmaf(ei_sh[k + 1], ei_sh[k + 1], ni1);
            ni2 = fmaf(ei_sh[k + 2], ei_sh[k + 2], ni2);
            ni3 = fmaf(ei_sh[k + 3], ei_sh[k + 3], ni3);
        }
        const float eni = sqrtf((ni0 + ni1) + (ni2 + ni3));
        #pragma unroll
        for (int jj = 0; jj < 2; ++jj) {
            const int j = t + jj * 256;
            const float4* er = (const float4*)(emb + ((size_t)j << 6));
            float d0 = 0.f, d1 = 0.f, d2 = 0.f, d3 = 0.f;
            float n0 = 0.f, n1 = 0.f, n2 = 0.f, n3 = 0.f;
            #pragma unroll
            for (int k4 = 0; k4 < 16; ++k4) {
                float4 u = er[k4];
                const float* e4 = ei_sh + k4 * 4;
                d0 = fmaf(u.x, e4[0], d0); d1 = fmaf(u.y, e4[1], d1);
                d2 = fmaf(u.z, e4[2], d2); d3 = fmaf(u.w, e4[3], d3);
                n0 = fmaf(u.x, u.x, n0);   n1 = fmaf(u.y, u.y, n1);
                n2 = fmaf(u.z, u.z, n2);   n3 = fmaf(u.w, u.w, n3);
            }
            float dot = (d0 + d1) + (d2 + d3);
            float enj = sqrtf((n0 + n1) + (n2 + n3));
            float xv = dot / (eni * enj);
            xv = fminf(fmaxf(xv, -0.99999f), 0.99999f);
            ang[j] = acosf(xv);
        }
        __syncthreads();
        if (wv == 0) {
            float m1 = 3.4e38f, m2 = 3.4e38f, ssum = 0.f;
            #pragma unroll
            for (int t8 = 0; t8 < 8; ++t8) {
                float a = ang[t8 * 64 + lane];
                ssum += a;
                if (a < m1) { m2 = m1; m1 = a; }
                else if (a < m2) m2 = a;
            }
            #pragma unroll
            for (int off = 32; off; off >>= 1) ssum += __shfl_xor(ssum, off, 64);
            #pragma unroll
            for (int off = 32; off; off >>= 1) {
                float o1 = __shfl_xor(m1, off, 64);
                float o2 = __shfl_xor(m2, off, 64);
                if (o1 < m1) { m2 = fminf(m1, o2); m1 = o1; }
                else          m2 = fminf(m2, o1);
            }
            float mean = ssum * (1.f / 512.f);
            float vs = 0.f;
            #pragma unroll
            for (int t8 = 0; t8 < 8; ++t8) {
                float tt = ang[t8 * 64 + lane] - mean;
                vs = fmaf(tt, tt, vs);
            }
            #pragma unroll
            for (int off = 32; off; off >>= 1) vs += __shfl_xor(vs, off, 64);
            if (lane == 0) { sv[i] = vs * (1.f / 511.f); sm[i] = m2; }
        }
    } else if (blockIdx.x < 1664) {
        // ---- W' fold (spin until all 1024 BN blocks done) ----
        if (t == 0) {
            while (__hip_atomic_load(tkt, __ATOMIC_ACQUIRE, __HIP_MEMORY_SCOPE_AGENT) < 1024)
                __builtin_amdgcn_s_sleep(8);
        }
        __syncthreads();
        __shared__ double sh_ad[4];
        const int blk = blockIdx.x - 1600;
        const int o = t & 63, fi = t >> 6;
        const int f = blk * 4 + fi;
        if (o == 0) {
            double s = (part[(4 * f) * 2]     + part[(4 * f + 1) * 2])
                     + (part[(4 * f + 2) * 2] + part[(4 * f + 3) * 2]);
            double q = (part[(4 * f) * 2 + 1]     + part[(4 * f + 1) * 2 + 1])
                     + (part[(4 * f + 2) * 2 + 1] + part[(4 * f + 3) * 2 + 1]);
            double mean = s * (1.0 / 65536.0);
            double var  = q * (1.0 / 65536.0) - mean * mean;
            sh_ad[fi] = (double)gamma[f] / sqrt(var + 1e-5);
        }
        __syncthreads();
        double s = 0.0;
        for (int c = 0; c < 64; ++c)
            s = fma((double)w2[o * 64 + c], (double)w1[c * 256 + f], s);
        double wp = s * sh_ad[fi];
        Wd[o * 256 + f] = wp;
        float wpf = (float)wp;
        unsigned short wh = f2bf(wpf);
        unsigned short wlv = f2bf(wpf - bf2f(wh));
        int mt = o >> 4, cq_ = o & 15, sK = f >> 5, qd_ = (f >> 3) & 3, j = f & 7;
        int idx = ((mt * 8 + sK) * 64 + qd_ * 16 + cq_) * 8 + j;
        whi[idx] = wh; wlo[idx] = wlv;
    } else {
        // ---- bias + zero accs (spin) ----
        if (t == 0) {
            while (__hip_atomic_load(tkt, __ATOMIC_ACQUIRE, __HIP_MEMORY_SCOPE_AGENT) < 1024)
                __builtin_amdgcn_s_sleep(8);
        }
        __syncthreads();
        __shared__ double cdl[256];
        __shared__ double red[4][64];
        __shared__ double tsh[64];
        {
            const int f = t;
            double s = (part[(4 * f) * 2]     + part[(4 * f + 1) * 2])
                     + (part[(4 * f + 2) * 2] + part[(4 * f + 3) * 2]);
            double q = (part[(4 * f) * 2 + 1]     + part[(4 * f + 1) * 2 + 1])
                     + (part[(4 * f + 2) * 2 + 1] + part[(4 * f + 3) * 2 + 1]);
            double mean = s * (1.0 / 65536.0);
            double var  = q * (1.0 / 65536.0) - mean * mean;
            double a = (double)gamma[f] / sqrt(var + 1e-5);
            cdl[f] = (double)beta[f] - mean * a;
        }
        __syncthreads();
        const int o = t & 63, p = t >> 6;
        double ss = 0.0;
        for (int j = 0; j < 64; ++j) {
            int fidx = p * 64 + j;
            ss = fma((double)w1[o * 256 + fidx], cdl[fidx], ss);
        }
        red[p][o] = ss; __syncthreads();
        if (t < 64) tsh[t] = (double)b1[t] + (red[0][t] + red[1][t]) + (red[2][t] + red[3][t]);
        __syncthreads();
        if (t < 64) {
            double bb = (double)b2[t];
            for (int c = 0; c < 64; ++c)
                bb = fma((double)w2[t * 64 + c], tsh[c], bb);
            bpd[t] = bb;
            bp[t]  = (float)bb;
        }
        if (t < 8) accs[t] = 0.f;
        if (t == 0) cnt[0] = 0;
    }
}

// ============================================================
// K3: 1024 blocks, one (b,h) each: MFMA GEMM + MFMA VQ.
// (R6 verbatim: LB(256,4), XCD swizzle, 2-deep x prefetch)
// ============================================================
__global__ __launch_bounds__(256, 4) void fused_gemm_vq(
    const float* __restrict__ x,
    const unsigned short* __restrict__ whi,
    const unsigned short* __restrict__ wlo,
    const float* __restrict__ bp,
    const float* __restrict__ emb,
    const float* __restrict__ e2,
    const unsigned short* __restrict__ ehi,
    const unsigned short* __restrict__ elo,
    float* __restrict__ accs,
    int* __restrict__ cnt, int* __restrict__ wl,
    float* __restrict__ zq)
{
    __shared__ __align__(16) unsigned smem[4880];
    enum { OAR = 0,   // [0,4096): XB hi/lo during GEMM -> z hi/lo -> VQ staging
           OE2 = 4096, OZ2 = 4608, ODT = 4672, OD2T = 4736, OIT = 4800 };
    float* e2s = (float*)(smem + OE2);
    float* z2s = (float*)(smem + OZ2);
    float* dT  = (float*)(smem + ODT);   // top-1 SCORE per token
    float* d2T = (float*)(smem + OD2T);  // top-2 SCORE per token
    int*   iT  = (int*)(smem + OIT);

    const int tid = threadIdx.x, lane = tid & 63, wv = tid >> 6;
    const int wvu = __builtin_amdgcn_readfirstlane(wv);
    const int lb = ((blockIdx.x & 7) << 7) | (blockIdx.x >> 3);   // XCD swizzle
    const int b = lb >> 6, h = lb & 63;
    const int cq = lane & 15, qd = lane >> 4;

    // A-frags (W' hi/lo), coalesced global b128 loads
    bf16v8 Ahi[8], Alo[8];
    #pragma unroll
    for (int s = 0; s < 8; ++s) {
        Ahi[s] = *(const bf16v8*)(whi + ((size_t)((wvu * 8 + s) * 64 + lane)) * 8);
        Alo[s] = *(const bf16v8*)(wlo + ((size_t)((wvu * 8 + s) * 64 + lane)) * 8);
    }
    float bpv[4];
    #pragma unroll
    for (int r = 0; r < 4; ++r) bpv[r] = bp[wvu * 16 + qd * 4 + r];
    e2s[tid]       = e2[tid];
    e2s[tid + 256] = e2[tid + 256];

    const float* xb = x + ((size_t)(b * 256 + wvu * 16) << 12) + (h << 6) + lane;
    float xva[16], xvb[16];
    #pragma unroll
    for (int i = 0; i < 16; ++i) xva[i] = xb[(size_t)i << 12];
    #pragma unroll
    for (int i = 0; i < 16; ++i) xvb[i] = xb[((size_t)(64 + i)) << 12];

    f32v4 acc[4];
    #pragma unroll
    for (int nt = 0; nt < 4; ++nt) acc[nt] = (f32v4){bpv[0], bpv[1], bpv[2], bpv[3]};

    // one GEMM chunk: stage CUR into XB, (reload CUR with chunk CHK+2), MFMAs
#define GEMM_CHUNK(CHK, CUR)                                                          \
    {                                                                                 \
        __syncthreads();                           /* XB free */                      \
        {                                                                             \
            unsigned hb[8], lbv[8];                                                   \
            _Pragma("unroll")                                                         \
            for (int p = 0; p < 8; ++p) {                                             \
                float a = CUR[2 * p], bq = CUR[2 * p + 1];                            \
                hb[p] = pack_bf2(a, bq);                                              \
                lbv[p] = pack_bf2(a - bfhi(a), bq - bfhi(bq));                        \
            }                                                                         \
            const int b0 = lane * 32 + (((2 * wvu) ^ (lane & 7)) << 2);               \
            const int b1_ = lane * 32 + (((2 * wvu + 1) ^ (lane & 7)) << 2);          \
            *(u32v4*)(smem + OAR + b0)         = (u32v4){hb[0], hb[1], hb[2], hb[3]}; \
            *(u32v4*)(smem + OAR + b1_)        = (u32v4){hb[4], hb[5], hb[6], hb[7]}; \
            *(u32v4*)(smem + OAR + 2048 + b0)  = (u32v4){lbv[0], lbv[1], lbv[2], lbv[3]}; \
            *(u32v4*)(smem + OAR + 2048 + b1_) = (u32v4){lbv[4], lbv[5], lbv[6], lbv[7]}; \
        }                                                                             \
        __syncthreads();                           /* XB ready */                     \
        if (CHK < 2) {                             /* reload CUR with chunk CHK+2 */  \
            const float* xb2 = xb + ((size_t)((CHK + 2) * 64) << 12);                 \
            _Pragma("unroll")                                                         \
            for (int i = 0; i < 16; ++i) CUR[i] = xb2[(size_t)i << 12];               \
        }                                                                             \
        _Pragma("unroll")                                                             \
        for (int st2 = 0; st2 < 2; ++st2) {                                           \
            const int s = CHK * 2 + st2;                                              \
            _Pragma("unroll")                                                         \
            for (int nt = 0; nt < 4; ++nt) {                                          \
                const int row = nt * 16 + cq;                                         \
                const int pos = row * 32 + (((st2 * 4 + qd) ^ (row & 7)) << 2);       \
                bf16v8 bh = *(const bf16v8*)(smem + OAR + pos);                       \
                bf16v8 bl = *(const bf16v8*)(smem + OAR + 2048 + pos);                \
                acc[nt] = __builtin_amdgcn_mfma_f32_16x16x32_bf16(Ahi[s], bh, acc[nt], 0, 0, 0); \
                acc[nt] = __builtin_amdgcn_mfma_f32_16x16x32_bf16(Ahi[s], bl, acc[nt], 0, 0, 0); \
                acc[nt] = __builtin_amdgcn_mfma_f32_16x16x32_bf16(Alo[s], bh, acc[nt], 0, 0, 0); \
            }                                                                         \
        }                                                                             \
    }

    GEMM_CHUNK(0, xva)
    GEMM_CHUNK(1, xvb)
    GEMM_CHUNK(2, xva)
    GEMM_CHUNK(3, xvb)
#undef GEMM_CHUNK

    __syncthreads();                               // last MFMA reads done

    // z2 + write z hi/lo into arena
    {
        float z2p[4];
        #pragma unroll
        for (int r = 0; r < 4; ++r) {
            float p2 = 0.f;
            #pragma unroll
            for (int nt = 0; nt < 4; ++nt) p2 = fmaf(acc[nt][r], acc[nt][r], p2);
            #pragma unroll
            for (int off = 1; off <= 8; off <<= 1) p2 += __shfl_xor(p2, off, 64);
            z2p[r] = p2;
        }
        if (cq == 0) {
            #pragma unroll
            for (int r = 0; r < 4; ++r) z2s[wvu * 16 + qd * 4 + r] = z2p[r];
        }
        unsigned short* ar = (unsigned short*)(smem + OAR);
        #pragma unroll
        for (int nt = 0; nt < 4; ++nt) {
            const int w = nt * 16 + cq;
            const int gz = w >> 3, kj = w & 7;
            #pragma unroll
            for (int r = 0; r < 4; ++r) {
                const int tok = wvu * 16 + qd * 4 + r;
                const int hw = tok * 64 + ((gz ^ (tok & 7)) << 3) + kj;
                unsigned short zh = f2bf(acc[nt][r]);
                ar[hw]        = zh;
                ar[4096 + hw] = f2bf(acc[nt][r] - bf2f(zh));
            }
        }
    }
    __syncthreads();                               // z arena ready

    const int x7 = cq & 7;
    bf16v8 vahi[2], valo[2];
    {
        const int rbase = (wvu * 16 + cq) * 32;
        #pragma unroll
        for (int s = 0; s < 2; ++s) {
            int pos = ((s * 4 + qd) ^ x7) * 4;
            vahi[s] = *(const bf16v8*)(smem + OAR + rbase + pos);
            valo[s] = *(const bf16v8*)(smem + OAR + 2048 + rbase + pos);
        }
    }
    __syncthreads();                               // arena becomes staging

    // stage code tiles 0,1 — distributed across waves
    {
        const float* gh = (const float*)ehi;
        const float* gl = (const float*)elo;
        load_lds16(gh + wvu * 256 + lane * 4,        smem + OAR + wvu * 256);
        load_lds16(gl + wvu * 256 + lane * 4,        smem + OAR + 1024 + wvu * 256);
        load_lds16(gh + 1024 + wvu * 256 + lane * 4, smem + OAR + 2048 + wvu * 256);
        load_lds16(gl + 1024 + wvu * 256 + lane * 4, smem + OAR + 3072 + wvu * 256);
    }

    float m1[4] = {-3.4e38f, -3.4e38f, -3.4e38f, -3.4e38f};
    float m2[4] = {-3.4e38f, -3.4e38f, -3.4e38f, -3.4e38f};
    int   i1[4] = {0, 0, 0, 0};
    const int p0 = (qd ^ x7) * 4, p1 = ((4 + qd) ^ x7) * 4;

    #pragma unroll 1
    for (int t2 = 0; t2 < 32; ++t2) {
        if ((t2 & 1) == 0) {
            __syncthreads();                       // staged tile (t2>>1) ready
            int st = t2 >> 1;
            if (st >= 1 && st < 15) {
                const float* gh = (const float*)ehi + (size_t)(st + 1) * 1024;
                const float* gl = (const float*)elo + (size_t)(st + 1) * 1024;
                unsigned* dst = smem + OAR + ((st + 1) & 1) * 2048;
                load_lds16(gh + wvu * 256 + lane * 4, dst + wvu * 256);
                load_lds16(gl + wvu * 256 + lane * 4, dst + 1024 + wvu * 256);
            }
        }
        const int rb = OAR + ((t2 >> 1) & 1) * 2048 + ((t2 & 1) * 16 + cq) * 32;
        bf16v8 bh0 = *(const bf16v8*)(smem + rb + p0);
        bf16v8 bh1 = *(const bf16v8*)(smem + rb + p1);
        bf16v8 bl0 = *(const bf16v8*)(smem + rb + 1024 + p0);
        bf16v8 bl1 = *(const bf16v8*)(smem + rb + 1024 + p1);
        const float eps = e2s[t2 * 16 + cq];
        f32v4 a = {0.f, 0.f, 0.f, 0.f};
        __builtin_amdgcn_s_setprio(1);
        a = __builtin_amdgcn_mfma_f32_16x16x32_bf16(vahi[0], bh0, a, 0, 0, 0);
        a = __builtin_amdgcn_mfma_f32_16x16x32_bf16(vahi[1], bh1, a, 0, 0, 0);
        a = __builtin_amdgcn_mfma_f32_16x16x32_bf16(vahi[0], bl0, a, 0, 0, 0);
        a = __builtin_amdgcn_mfma_f32_16x16x32_bf16(vahi[1], bl1, a, 0, 0, 0);
        a = __builtin_amdgcn_mfma_f32_16x16x32_bf16(valo[0], bh0, a, 0, 0, 0);
        a = __builtin_amdgcn_mfma_f32_16x16x32_bf16(valo[1], bh1, a, 0, 0, 0);
        __builtin_amdgcn_s_setprio(0);
        const int n = t2 * 16 + cq;
        #pragma unroll
        for (int r = 0; r < 4; ++r) {
            float s = fmaf(-0.5f, eps, a[r]);      // score = dot - e2/2
            bool gt = s > m1[r];
            m2[r] = fminf(fmaxf(s, m2[r]), m1[r]);
            i1[r] = gt ? n : i1[r];
            m1[r] = fmaxf(s, m1[r]);
        }
    }

    // merge top-2 (score domain: prefer larger s; on ties lower index)
    #pragma unroll
    for (int r = 0; r < 4; ++r) {
        #pragma unroll
        for (int off = 1; off <= 8; off <<= 1) {
            float o1 = __shfl_xor(m1[r], off, 64);
            float o2 = __shfl_xor(m2[r], off, 64);
            int   oi = __shfl_xor(i1[r], off, 64);
            if (o1 > m1[r] || (o1 == m1[r] && oi < i1[r])) {
                m2[r] = fmaxf(m1[r], o2); m1[r] = o1; i1[r] = oi;
            } else {
                m2[r] = fmaxf(m2[r], o1);
            }
        }
    }
    if (cq == 0) {
        #pragma unroll
        for (int r = 0; r < 4; ++r) {
            int tok = wvu * 16 + qd * 4 + r;
            dT[tok] = m1[r]; d2T[tok] = m2[r]; iT[tok] = i1[r];
        }
    }
    __syncthreads();

    if (wv == 0) {
        float s1 = dT[lane], s2 = d2T[lane];
        if (s1 - s2 < MARGIN * 0.5f) {             // d2-d1 = 2(s1-s2) < MARGIN
            int pos = atomicAdd(cnt, 1);
            if (pos < CAP) wl[pos] = ((b << 6) + lane) * 64 + h;
        }
        float ms = z2s[lane] - 2.f * s1;
        #pragma unroll
        for (int off = 32; off; off >>= 1) ms += __shfl_xor(ms, off, 64);
        if (lane == 0) atomicAdd(accs + 0, ms);
    }
    __syncthreads();

    float* zrow = zq + ((size_t)(b * 64) << 12) + (h << 6) + lane;
    #pragma unroll
    for (int cc = 0; cc < 16; ++cc) {
        int c = wvu * 16 + cc;
        int id = iT[c];
        zrow[(size_t)c << 12] = emb[(id << 6) + lane];
    }
}

// ============================================================
// K4: fp64 refinement, ONE token per block (blocks 0..2047) + finalize
//     (block 2048; also reduces sv/sm stats partials). (R6 verbatim)
// ============================================================
__global__ __launch_bounds__(256) void refine_fin(
    const float* __restrict__ x,
    const double* __restrict__ Wd,
    const double* __restrict__ bpd,
    const float* __restrict__ emb,
    const float* __restrict__ eft,
    const int* __restrict__ cnt, const int* __restrict__ wl,
    float* __restrict__ zq,
    const float* __restrict__ accs, const float* __restrict__ en,
    const float* __restrict__ sv, const float* __restrict__ sm,
    const float* __restrict__ r, float* __restrict__ out)
{
    const int tid = threadIdx.x, lane = tid & 63, wv = tid >> 6;

    if (blockIdx.x == 2048) {
        if (wv == 0) {
            float hs = 0.f, rs = 0.f, cv = 0.f, tm = 0.f;
            #pragma unroll
            for (int jj = 0; jj < 8; ++jj) {
                int n = (jj << 6) + lane;
                float rv = r[n];
                float d = rv - en[n];
                hs = fmaf(d, d, hs);
                rs += fminf(fmaxf(rv, 0.9f), 1.1f);
                cv += sv[n];
                tm += sm[n];
            }
            #pragma unroll
            for (int off = 32; off; off >>= 1) {
                hs += __shfl_xor(hs, off, 64); rs += __shfl_xor(rs, off, 64);
                cv += __shfl_xor(cv, off, 64); tm += __shfl_xor(tm, off, 64);
            }
            if (lane == 0) {
                float hsw    = hs * (1.f / 512.f);
                float mean_r = rs * (1.f / 512.f);
                float mse    = accs[0] * (1.f / 4194304.f);
                float cbv    = cv * (1.f / 512.f);
                float tmd    = tm * (1.f / 512.f);
                float loss   = 2.f * mse + hsw + (cbv - tmd);
                out[0]       = loss;
                out[4194305] = cbv;
                out[4194306] = tmd;
                out[4194307] = hsw;
                out[4194308] = 0.f;
                out[4194309] = mean_r;
            }
        }
        return;
    }

    int count = cnt[0]; if (count > CAP) count = CAP;
    const int it = blockIdx.x;
    if (it >= count) return;

    __shared__ double zp[4][64];
    __shared__ double zs[64];
    __shared__ double dsh[4];
    __shared__ int    ish[4];

    const int r2 = wl[it];
    const int b = r2 >> 12, c = (r2 >> 6) & 63, h = r2 & 63;

    // z compute: wave wv covers f in [wv*64, wv*64+64), lane = w; 8-way ILP
    {
        const float* xp = x + (((size_t)(b * 256 + wv * 64)) << 12) + (h << 6) + lane;
        const double* wrow = Wd + c * 256 + wv * 64;
        double zc0 = 0.0, zc1 = 0.0, zc2 = 0.0, zc3 = 0.0;
        double zc4 = 0.0, zc5 = 0.0, zc6 = 0.0, zc7 = 0.0;
        #pragma unroll
        for (int f = 0; f < 64; f += 8) {
            float a0 = xp[(size_t)(f + 0) << 12];
            float a1 = xp[(size_t)(f + 1) << 12];
            float a2 = xp[(size_t)(f + 2) << 12];
            float a3 = xp[(size_t)(f + 3) << 12];
            float a4 = xp[(size_t)(f + 4) << 12];
            float a5 = xp[(size_t)(f + 5) << 12];
            float a6 = xp[(size_t)(f + 6) << 12];
            float a7 = xp[(size_t)(f + 7) << 12];
            zc0 = fma(wrow[f + 0], (double)a0, zc0);
            zc1 = fma(wrow[f + 1], (double)a1, zc1);
            zc2 = fma(wrow[f + 2], (double)a2, zc2);
            zc3 = fma(wrow[f + 3], (double)a3, zc3);
            zc4 = fma(wrow[f + 4], (double)a4, zc4);
            zc5 = fma(wrow[f + 5], (double)a5, zc5);
            zc6 = fma(wrow[f + 6], (double)a6, zc6);
            zc7 = fma(wrow[f + 7], (double)a7, zc7);
        }
        zp[wv][lane] = ((zc0 + zc1) + (zc2 + zc3)) + ((zc4 + zc5) + (zc6 + zc7));
    }
    __syncthreads();
    if (tid < 64) zs[tid] = (zp[0][tid] + zp[1][tid]) + (zp[2][tid] + zp[3][tid]) + bpd[c];
    __syncthreads();

    // distances for candidates n0 = tid, n1 = tid+256; 8 fp64 chains
    const int n0 = tid, n1 = tid + 256;
    double d0a = 0.0, d0b = 0.0, d0c = 0.0, d0d = 0.0;
    double d1a = 0.0, d1b = 0.0, d1c = 0.0, d1d = 0.0;
    #pragma unroll 4
    for (int k = 0; k < 64; k += 4) {
        double z0 = zs[k], z1 = zs[k + 1], z2 = zs[k + 2], z3 = zs[k + 3];
        double t;
        t = z0 - (double)eft[((k + 0) << 9) + n0]; d0a = fma(t, t, d0a);
        t = z1 - (double)eft[((k + 1) << 9) + n0]; d0b = fma(t, t, d0b);
        t = z2 - (double)eft[((k + 2) << 9) + n0]; d0c = fma(t, t, d0c);
        t = z3 - (double)eft[((k + 3) << 9) + n0]; d0d = fma(t, t, d0d);
        t = z0 - (double)eft[((k + 0) << 9) + n1]; d1a = fma(t, t, d1a);
        t = z1 - (double)eft[((k + 1) << 9) + n1]; d1b = fma(t, t, d1b);
        t = z2 - (double)eft[((k + 2) << 9) + n1]; d1c = fma(t, t, d1c);
        t = z3 - (double)eft[((k + 3) << 9) + n1]; d1d = fma(t, t, d1d);
    }
    double d0 = (d0a + d0b) + (d0c + d0d);
    double d1 = (d1a + d1b) + (d1c + d1d);
    double dm; int im;
    if (d1 < d0) { dm = d1; im = n1; } else { dm = d0; im = n0; }  // n0 < n1

    // wave shuffle-min (value, index; tie -> lower index)
    #pragma unroll
    for (int off = 32; off; off >>= 1) {
        double od = __shfl_xor(dm, off, 64);
        int    oi = __shfl_xor(im, off, 64);
        if (od < dm || (od == dm && oi < im)) { dm = od; im = oi; }
    }
    if (lane == 0) { dsh[wv] = dm; ish[wv] = im; }
    __syncthreads();

    if (tid < 64) {
        double best = dsh[0]; int bi = ish[0];
        #pragma unroll
        for (int wq = 1; wq < 4; ++wq) {
            double od = dsh[wq]; int oi = ish[wq];
            if (od < best || (od == best && oi < bi)) { best = od; bi = oi; }
        }
        zq[((size_t)r2 << 6) + tid] = emb[(bi << 6) + tid];
    }
}

// ============================================================
extern "C" void kernel_launch(void* const* d_in, const int* in_sizes, int n_in,
                              void* d_out, int out_size, void* d_ws, size_t ws_size,
                              hipStream_t stream) {
    const float* x   = (const float*)d_in[0];
    const float* g1  = (const float*)d_in[1];
    const float* be1 = (const float*)d_in[2];
    const float* w1  = (const float*)d_in[3];
    const float* b1  = (const float*)d_in[4];
    const float* w2  = (const float*)d_in[5];
    const float* b2  = (const float*)d_in[6];
    const float* emb = (const float*)d_in[7];
    const float* r   = (const float*)d_in[8];
    float* ws = (float*)d_ws;
    float* out = (float*)d_out;

    double* WD   = (double*)(ws + WS_WD);
    double* BPD  = (double*)(ws + WS_BPD);
    double* PART = (double*)(ws + WS_PART);
    int*    CNT  = (int*)(ws + WS_CNT);
    int*    WL   = (int*)(ws + WS_WL);
    int*    TKT  = (int*)(ws + WS_TKT);
    unsigned short* WHI = (unsigned short*)(ws + WS_WHI);
    unsigned short* WLO = (unsigned short*)(ws + WS_WLO);
    unsigned short* EHI = (unsigned short*)(ws + WS_EHI);
    unsigned short* ELO = (unsigned short*)(ws + WS_ELO);

    hipMemsetAsync(TKT, 0, 4, stream);
    bn_stats_prep<<<1665, 256, 0, stream>>>(x, PART, emb, w1, w2, b1, b2, g1, be1,
                                            ws + WS_EFT, ws + WS_EN, ws + WS_E2,
                                            EHI, ELO, ws + WS_SV, ws + WS_SM,
                                            WHI, WLO, WD, BPD, ws + WS_BP,
                                            ws + WS_ACC, CNT, TKT);
    fused_gemm_vq<<<1024, 256, 0, stream>>>(x, WHI, WLO, ws + WS_BP,
                                            emb, ws + WS_E2,
                                            EHI, ELO, ws + WS_ACC, CNT, WL, out + 1);
    refine_fin<<<2049, 256, 0, stream>>>(x, WD, BPD, emb, ws + WS_EFT, CNT, WL,
                                         out + 1, ws + WS_ACC, ws + WS_EN,
                                         ws + WS_SV, ws + WS_SM, r, out);
}

// Round 9
// 181.480 us; speedup vs baseline: 1.2126x; 1.2126x over previous
//
#include <hip/hip_runtime.h>
#include <math.h>

// ---------- problem constants ----------
// B=16, F=256, C=64, H=64, W=64, N_E=512. Inputs fp32, outputs fp32.
// tokens: rows r=(b*64+c)*64+h of 64 w-values; 65536 tokens total.
// bf16-split MFMA GEMM + bf16-split MFMA VQ; near-ties re-resolved in fp64.
// R9: R6 config (best, 181.7) + VQ loop unroll 2 (cross-iteration pipelining).

#define CAP    2048
#define MARGIN 4e-3f

// ---------- workspace layout (float offsets) ----------
#define WS_WHI  0        // [16384 ushort] W' hi bf16, A-frag order
#define WS_WLO  8192     // [16384 ushort] W' lo bf16
#define WS_BP   16384    // [64]
#define WS_EN   16448    // [512]
#define WS_E2   16960    // [512]
#define WS_ACC  17472    // [8]
#define WS_CNT  17480    // [8]
#define WS_WL   17488    // [2048]
#define WS_EFT  19536    // [64*512] fp32 emb^T
#define WS_WD   52304    // [16384 dbl]
#define WS_BPD  85072    // [64 dbl]
#define WS_EHI  85200    // [32768 ushort] emb hi bf16, XOR-swizzled granules
#define WS_ELO  101584   // [32768 ushort] emb lo bf16, swizzled
#define WS_PART 117968   // [2048 dbl] bn partials (1024 blocks x {s,q})
#define WS_SV   122064   // [512] cb-stats per-row variance partials
#define WS_SM   122576   // [512] cb-stats per-row 2nd-min partials

typedef __attribute__((ext_vector_type(8))) __bf16 bf16v8;
typedef __attribute__((ext_vector_type(2))) __bf16 bf16v2;
typedef __attribute__((ext_vector_type(4))) float  f32v4;
typedef __attribute__((ext_vector_type(4))) unsigned u32v4;

__device__ __forceinline__ unsigned short f2bf(float f) {
    __bf16 h = (__bf16)f;
    return __builtin_bit_cast(unsigned short, h);
}
__device__ __forceinline__ float bf2f(unsigned short h) {
    union { unsigned u; float f; } v; v.u = ((unsigned)h) << 16; return v.f;
}
__device__ __forceinline__ unsigned pack_bf2(float a, float b) {
    bf16v2 v = { (__bf16)a, (__bf16)b };
    return __builtin_bit_cast(unsigned, v);
}
__device__ __forceinline__ float bfhi(float a) {
    return (float)(__bf16)a;
}
__device__ __forceinline__ void load_lds16(const float* g, unsigned* l) {
    __builtin_amdgcn_global_load_lds((const __attribute__((address_space(1))) void*)g,
                                     (__attribute__((address_space(3))) void*)l, 16, 0, 0);
}

// ============================================================
// K1: blocks 0..1023: BN partials (memory-bound). blocks 1024..1087:
//     emb prep. 1088..1599: cb angular stats (VALU, hides under BN).
// ============================================================
__global__ __launch_bounds__(256) void bn_stats_prep(
    const float* __restrict__ x, double* __restrict__ part,
    const float* __restrict__ emb,
    float* __restrict__ eft, float* __restrict__ en, float* __restrict__ e2,
    unsigned short* __restrict__ ehi, unsigned short* __restrict__ elo,
    float* __restrict__ sv, float* __restrict__ sm)
{
    const int t = threadIdx.x;

    if (blockIdx.x < 1024) {
        // ---- BN partial sums ----
        const int f = blockIdx.x >> 2, ch = blockIdx.x & 3;
        double s0 = 0.0, s1 = 0.0, q0 = 0.0, q1 = 0.0, q2 = 0.0, q3 = 0.0;
        #pragma unroll
        for (int bb = 0; bb < 4; ++bb) {
            const int b = ch * 4 + bb;
            const float4* p = (const float4*)(x + ((size_t)(b * 256 + f) << 12));
            #pragma unroll
            for (int ii = 0; ii < 4; ++ii) {
                float4 u = p[t + ii * 256];
                double dx = u.x, dy = u.y, dz = u.z, dw = u.w;
                s0 += dx + dy; s1 += dz + dw;
                q0 = fma(dx, dx, q0); q1 = fma(dy, dy, q1);
                q2 = fma(dz, dz, q2); q3 = fma(dw, dw, q3);
            }
        }
        double s = s0 + s1, q = (q0 + q1) + (q2 + q3);
        #pragma unroll
        for (int off = 32; off; off >>= 1) { s += __shfl_xor(s, off, 64); q += __shfl_xor(q, off, 64); }
        __shared__ double sh[8];
        const int wv = t >> 6;
        if ((t & 63) == 0) { sh[wv * 2] = s; sh[wv * 2 + 1] = q; }
        __syncthreads();
        if (t == 0) {
            part[blockIdx.x * 2]     = (sh[0] + sh[2]) + (sh[4] + sh[6]);
            part[blockIdx.x * 2 + 1] = (sh[1] + sh[3]) + (sh[5] + sh[7]);
        }
    } else if (blockIdx.x < 1088) {
        // ---- embedding prep: 8 rows per block ----
        const int blk = blockIdx.x - 1024;
        const int lane = t & 63, wv = t >> 6;
        #pragma unroll
        for (int rr = 0; rr < 2; ++rr) {
            int n = blk * 8 + rr * 4 + wv;
            float v = emb[n * 64 + lane];
            eft[lane * 512 + n] = v;
            unsigned short hb = f2bf(v);
            unsigned short lb = f2bf(v - bf2f(hb));
            int pos = (lane >> 3) ^ (n & 7);          // XOR-swizzled granule
            ehi[n * 64 + pos * 8 + (lane & 7)] = hb;
            elo[n * 64 + pos * 8 + (lane & 7)] = lb;
            float qq = v * v;
            #pragma unroll
            for (int off = 32; off; off >>= 1) qq += __shfl_xor(qq, off, 64);
            if (lane == 0) { e2[n] = qq; en[n] = sqrtf(qq); }
        }
    } else {
        // ---- codebook angular stats for row i (reads emb directly) ----
        const int i = blockIdx.x - 1088;
        const int lane = t & 63, wv = t >> 6;
        __shared__ float ei_sh[64];
        __shared__ float ang[512];
        if (t < 64) ei_sh[t] = emb[(i << 6) + t];
        __syncthreads();
        float ni0 = 0.f, ni1 = 0.f, ni2 = 0.f, ni3 = 0.f;
        #pragma unroll
        for (int k = 0; k < 64; k += 4) {
            ni0 = fmaf(ei_sh[k + 0], ei_sh[k + 0], ni0);
            ni1 = fmaf(ei_sh[k + 1], ei_sh[k + 1], ni1);
            ni2 = fmaf(ei_sh[k + 2], ei_sh[k + 2], ni2);
            ni3 = fmaf(ei_sh[k + 3], ei_sh[k + 3], ni3);
        }
        const float eni = sqrtf((ni0 + ni1) + (ni2 + ni3));
        #pragma unroll
        for (int jj = 0; jj < 2; ++jj) {
            const int j = t + jj * 256;
            const float4* er = (const float4*)(emb + ((size_t)j << 6));
            float d0 = 0.f, d1 = 0.f, d2 = 0.f, d3 = 0.f;
            float n0 = 0.f, n1 = 0.f, n2 = 0.f, n3 = 0.f;
            #pragma unroll
            for (int k4 = 0; k4 < 16; ++k4) {
                float4 u = er[k4];
                const float* e4 = ei_sh + k4 * 4;
                d0 = fmaf(u.x, e4[0], d0); d1 = fmaf(u.y, e4[1], d1);
                d2 = fmaf(u.z, e4[2], d2); d3 = fmaf(u.w, e4[3], d3);
                n0 = fmaf(u.x, u.x, n0);   n1 = fmaf(u.y, u.y, n1);
                n2 = fmaf(u.z, u.z, n2);   n3 = fmaf(u.w, u.w, n3);
            }
            float dot = (d0 + d1) + (d2 + d3);
            float enj = sqrtf((n0 + n1) + (n2 + n3));
            float xv = dot / (eni * enj);
            xv = fminf(fmaxf(xv, -0.99999f), 0.99999f);
            ang[j] = acosf(xv);
        }
        __syncthreads();
        if (wv == 0) {
            float m1 = 3.4e38f, m2 = 3.4e38f, ssum = 0.f;
            #pragma unroll
            for (int t8 = 0; t8 < 8; ++t8) {
                float a = ang[t8 * 64 + lane];
                ssum += a;
                if (a < m1) { m2 = m1; m1 = a; }
                else if (a < m2) m2 = a;
            }
            #pragma unroll
            for (int off = 32; off; off >>= 1) ssum += __shfl_xor(ssum, off, 64);
            #pragma unroll
            for (int off = 32; off; off >>= 1) {
                float o1 = __shfl_xor(m1, off, 64);
                float o2 = __shfl_xor(m2, off, 64);
                if (o1 < m1) { m2 = fminf(m1, o2); m1 = o1; }
                else          m2 = fminf(m2, o1);
            }
            float mean = ssum * (1.f / 512.f);
            float vs = 0.f;
            #pragma unroll
            for (int t8 = 0; t8 < 8; ++t8) {
                float tt = ang[t8 * 64 + lane] - mean;
                vs = fmaf(tt, tt, vs);
            }
            #pragma unroll
            for (int off = 32; off; off >>= 1) vs += __shfl_xor(vs, off, 64);
            if (lane == 0) { sv[i] = vs * (1.f / 511.f); sm[i] = m2; }
        }
    }
}

// ============================================================
// K2: prep. Blocks 0..63: a_f + W' fold (fp64) + W' bf16 hi/lo A-frag split.
//     Block 64: c_f + bias + zero accs/cnt.
// ============================================================
__global__ __launch_bounds__(256) void prep(
    const float* __restrict__ w1, const float* __restrict__ w2,
    const float* __restrict__ b1, const float* __restrict__ b2,
    const float* __restrict__ gamma, const float* __restrict__ beta,
    const double* __restrict__ part,
    unsigned short* __restrict__ whi, unsigned short* __restrict__ wlo,
    double* __restrict__ Wd,
    double* __restrict__ bpd, float* __restrict__ bp,
    float* __restrict__ accs, int* __restrict__ cnt)
{
    __shared__ double sh_ad[4];
    __shared__ double cdl[256];
    __shared__ double red[4][64];
    __shared__ double tsh[64];
    const int t = threadIdx.x;

    if (blockIdx.x < 64) {
        const int o = t & 63, fi = t >> 6;
        const int f = blockIdx.x * 4 + fi;
        if (o == 0) {
            double s = (part[(4 * f) * 2]     + part[(4 * f + 1) * 2])
                     + (part[(4 * f + 2) * 2] + part[(4 * f + 3) * 2]);
            double q = (part[(4 * f) * 2 + 1]     + part[(4 * f + 1) * 2 + 1])
                     + (part[(4 * f + 2) * 2 + 1] + part[(4 * f + 3) * 2 + 1]);
            double mean = s * (1.0 / 65536.0);
            double var  = q * (1.0 / 65536.0) - mean * mean;
            sh_ad[fi] = (double)gamma[f] / sqrt(var + 1e-5);
        }
        __syncthreads();
        double s = 0.0;
        for (int c = 0; c < 64; ++c)
            s = fma((double)w2[o * 64 + c], (double)w1[c * 256 + f], s);
        double wp = s * sh_ad[fi];
        Wd[o * 256 + f] = wp;
        {
            float wpf = (float)wp;
            unsigned short wh = f2bf(wpf);
            unsigned short wlv = f2bf(wpf - bf2f(wh));
            int mt = o >> 4, cq_ = o & 15, sK = f >> 5, qd_ = (f >> 3) & 3, j = f & 7;
            int idx = ((mt * 8 + sK) * 64 + qd_ * 16 + cq_) * 8 + j;
            whi[idx] = wh; wlo[idx] = wlv;
        }
    } else {
        {
            const int f = t;
            double s = (part[(4 * f) * 2]     + part[(4 * f + 1) * 2])
                     + (part[(4 * f + 2) * 2] + part[(4 * f + 3) * 2]);
            double q = (part[(4 * f) * 2 + 1]     + part[(4 * f + 1) * 2 + 1])
                     + (part[(4 * f + 2) * 2 + 1] + part[(4 * f + 3) * 2 + 1]);
            double mean = s * (1.0 / 65536.0);
            double var  = q * (1.0 / 65536.0) - mean * mean;
            double a = (double)gamma[f] / sqrt(var + 1e-5);
            cdl[f] = (double)beta[f] - mean * a;
        }
        __syncthreads();
        const int o = t & 63, p = t >> 6;
        double ss = 0.0;
        for (int j = 0; j < 64; ++j) {
            int fidx = p * 64 + j;
            ss = fma((double)w1[o * 256 + fidx], cdl[fidx], ss);
        }
        red[p][o] = ss; __syncthreads();
        if (t < 64) tsh[t] = (double)b1[t] + (red[0][t] + red[1][t]) + (red[2][t] + red[3][t]);
        __syncthreads();
        if (t < 64) {
            double bb = (double)b2[t];
            for (int c = 0; c < 64; ++c)
                bb = fma((double)w2[t * 64 + c], tsh[c], bb);
            bpd[t] = bb;
            bp[t]  = (float)bb;
        }
        if (t < 8) accs[t] = 0.f;
        if (t == 0) cnt[0] = 0;
    }
}

// ============================================================
// K3: 1024 blocks, one (b,h) each: MFMA GEMM + MFMA VQ.
// R6 verbatim except: VQ loop unroll 2 — consecutive iterations are
// independent (fresh acc, same staged buffer), so pairing them lets the
// scheduler overlap iter i+1's ds_reads/MFMAs with iter i's chain.
// ============================================================
__global__ __launch_bounds__(256, 4) void fused_gemm_vq(
    const float* __restrict__ x,
    const unsigned short* __restrict__ whi,
    const unsigned short* __restrict__ wlo,
    const float* __restrict__ bp,
    const float* __restrict__ emb,
    const float* __restrict__ e2,
    const unsigned short* __restrict__ ehi,
    const unsigned short* __restrict__ elo,
    float* __restrict__ accs,
    int* __restrict__ cnt, int* __restrict__ wl,
    float* __restrict__ zq)
{
    __shared__ __align__(16) unsigned smem[4880];
    enum { OAR = 0,   // [0,4096): XB hi/lo during GEMM -> z hi/lo -> VQ staging
           OE2 = 4096, OZ2 = 4608, ODT = 4672, OD2T = 4736, OIT = 4800 };
    float* e2s = (float*)(smem + OE2);
    float* z2s = (float*)(smem + OZ2);
    float* dT  = (float*)(smem + ODT);   // top-1 SCORE per token
    float* d2T = (float*)(smem + OD2T);  // top-2 SCORE per token
    int*   iT  = (int*)(smem + OIT);

    const int tid = threadIdx.x, lane = tid & 63, wv = tid >> 6;
    const int wvu = __builtin_amdgcn_readfirstlane(wv);
    const int lb = ((blockIdx.x & 7) << 7) | (blockIdx.x >> 3);   // XCD swizzle
    const int b = lb >> 6, h = lb & 63;
    const int cq = lane & 15, qd = lane >> 4;

    // A-frags (W' hi/lo), coalesced global b128 loads
    bf16v8 Ahi[8], Alo[8];
    #pragma unroll
    for (int s = 0; s < 8; ++s) {
        Ahi[s] = *(const bf16v8*)(whi + ((size_t)((wvu * 8 + s) * 64 + lane)) * 8);
        Alo[s] = *(const bf16v8*)(wlo + ((size_t)((wvu * 8 + s) * 64 + lane)) * 8);
    }
    float bpv[4];
    #pragma unroll
    for (int r = 0; r < 4; ++r) bpv[r] = bp[wvu * 16 + qd * 4 + r];
    e2s[tid]       = e2[tid];
    e2s[tid + 256] = e2[tid + 256];

    const float* xb = x + ((size_t)(b * 256 + wvu * 16) << 12) + (h << 6) + lane;
    float xva[16], xvb[16];
    #pragma unroll
    for (int i = 0; i < 16; ++i) xva[i] = xb[(size_t)i << 12];
    #pragma unroll
    for (int i = 0; i < 16; ++i) xvb[i] = xb[((size_t)(64 + i)) << 12];

    f32v4 acc[4];
    #pragma unroll
    for (int nt = 0; nt < 4; ++nt) acc[nt] = (f32v4){bpv[0], bpv[1], bpv[2], bpv[3]};

    // one GEMM chunk: stage CUR into XB, (reload CUR with chunk CHK+2), MFMAs
#define GEMM_CHUNK(CHK, CUR)                                                          \
    {                                                                                 \
        __syncthreads();                           /* XB free */                      \
        {                                                                             \
            unsigned hb[8], lbv[8];                                                   \
            _Pragma("unroll")                                                         \
            for (int p = 0; p < 8; ++p) {                                             \
                float a = CUR[2 * p], bq = CUR[2 * p + 1];                            \
                hb[p] = pack_bf2(a, bq);                                              \
                lbv[p] = pack_bf2(a - bfhi(a), bq - bfhi(bq));                        \
            }                                                                         \
            const int b0 = lane * 32 + (((2 * wvu) ^ (lane & 7)) << 2);               \
            const int b1_ = lane * 32 + (((2 * wvu + 1) ^ (lane & 7)) << 2);          \
            *(u32v4*)(smem + OAR + b0)         = (u32v4){hb[0], hb[1], hb[2], hb[3]}; \
            *(u32v4*)(smem + OAR + b1_)        = (u32v4){hb[4], hb[5], hb[6], hb[7]}; \
            *(u32v4*)(smem + OAR + 2048 + b0)  = (u32v4){lbv[0], lbv[1], lbv[2], lbv[3]}; \
            *(u32v4*)(smem + OAR + 2048 + b1_) = (u32v4){lbv[4], lbv[5], lbv[6], lbv[7]}; \
        }                                                                             \
        __syncthreads();                           /* XB ready */                     \
        if (CHK < 2) {                             /* reload CUR with chunk CHK+2 */  \
            const float* xb2 = xb + ((size_t)((CHK + 2) * 64) << 12);                 \
            _Pragma("unroll")                                                         \
            for (int i = 0; i < 16; ++i) CUR[i] = xb2[(size_t)i << 12];               \
        }                                                                             \
        _Pragma("unroll")                                                             \
        for (int st2 = 0; st2 < 2; ++st2) {                                           \
            const int s = CHK * 2 + st2;                                              \
            _Pragma("unroll")                                                         \
            for (int nt = 0; nt < 4; ++nt) {                                          \
                const int row = nt * 16 + cq;                                         \
                const int pos = row * 32 + (((st2 * 4 + qd) ^ (row & 7)) << 2);       \
                bf16v8 bh = *(const bf16v8*)(smem + OAR + pos);                       \
                bf16v8 bl = *(const bf16v8*)(smem + OAR + 2048 + pos);                \
                acc[nt] = __builtin_amdgcn_mfma_f32_16x16x32_bf16(Ahi[s], bh, acc[nt], 0, 0, 0); \
                acc[nt] = __builtin_amdgcn_mfma_f32_16x16x32_bf16(Ahi[s], bl, acc[nt], 0, 0, 0); \
                acc[nt] = __builtin_amdgcn_mfma_f32_16x16x32_bf16(Alo[s], bh, acc[nt], 0, 0, 0); \
            }                                                                         \
        }                                                                             \
    }

    GEMM_CHUNK(0, xva)
    GEMM_CHUNK(1, xvb)
    GEMM_CHUNK(2, xva)
    GEMM_CHUNK(3, xvb)
#undef GEMM_CHUNK

    __syncthreads();                               // last MFMA reads done

    // z2 + write z hi/lo into arena
    {
        float z2p[4];
        #pragma unroll
        for (int r = 0; r < 4; ++r) {
            float p2 = 0.f;
            #pragma unroll
            for (int nt = 0; nt < 4; ++nt) p2 = fmaf(acc[nt][r], acc[nt][r], p2);
            #pragma unroll
            for (int off = 1; off <= 8; off <<= 1) p2 += __shfl_xor(p2, off, 64);
            z2p[r] = p2;
        }
        if (cq == 0) {
            #pragma unroll
            for (int r = 0; r < 4; ++r) z2s[wvu * 16 + qd * 4 + r] = z2p[r];
        }
        unsigned short* ar = (unsigned short*)(smem + OAR);
        #pragma unroll
        for (int nt = 0; nt < 4; ++nt) {
            const int w = nt * 16 + cq;
            const int gz = w >> 3, kj = w & 7;
            #pragma unroll
            for (int r = 0; r < 4; ++r) {
                const int tok = wvu * 16 + qd * 4 + r;
                const int hw = tok * 64 + ((gz ^ (tok & 7)) << 3) + kj;
                unsigned short zh = f2bf(acc[nt][r]);
                ar[hw]        = zh;
                ar[4096 + hw] = f2bf(acc[nt][r] - bf2f(zh));
            }
        }
    }
    __syncthreads();                               // z arena ready

    const int x7 = cq & 7;
    bf16v8 vahi[2], valo[2];
    {
        const int rbase = (wvu * 16 + cq) * 32;
        #pragma unroll
        for (int s = 0; s < 2; ++s) {
            int pos = ((s * 4 + qd) ^ x7) * 4;
            vahi[s] = *(const bf16v8*)(smem + OAR + rbase + pos);
            valo[s] = *(const bf16v8*)(smem + OAR + 2048 + rbase + pos);
        }
    }
    __syncthreads();                               // arena becomes staging

    // stage code tiles 0,1 — distributed across waves
    {
        const float* gh = (const float*)ehi;
        const float* gl = (const float*)elo;
        load_lds16(gh + wvu * 256 + lane * 4,        smem + OAR + wvu * 256);
        load_lds16(gl + wvu * 256 + lane * 4,        smem + OAR + 1024 + wvu * 256);
        load_lds16(gh + 1024 + wvu * 256 + lane * 4, smem + OAR + 2048 + wvu * 256);
        load_lds16(gl + 1024 + wvu * 256 + lane * 4, smem + OAR + 3072 + wvu * 256);
    }

    float m1[4] = {-3.4e38f, -3.4e38f, -3.4e38f, -3.4e38f};
    float m2[4] = {-3.4e38f, -3.4e38f, -3.4e38f, -3.4e38f};
    int   i1[4] = {0, 0, 0, 0};
    const int p0 = (qd ^ x7) * 4, p1 = ((4 + qd) ^ x7) * 4;

    #pragma unroll 2
    for (int t2 = 0; t2 < 32; ++t2) {
        if ((t2 & 1) == 0) {
            __syncthreads();                       // staged tile (t2>>1) ready
            int st = t2 >> 1;
            if (st >= 1 && st < 15) {
                const float* gh = (const float*)ehi + (size_t)(st + 1) * 1024;
                const float* gl = (const float*)elo + (size_t)(st + 1) * 1024;
                unsigned* dst = smem + OAR + ((st + 1) & 1) * 2048;
                load_lds16(gh + wvu * 256 + lane * 4, dst + wvu * 256);
                load_lds16(gl + wvu * 256 + lane * 4, dst + 1024 + wvu * 256);
            }
        }
        const int rb = OAR + ((t2 >> 1) & 1) * 2048 + ((t2 & 1) * 16 + cq) * 32;
        bf16v8 bh0 = *(const bf16v8*)(smem + rb + p0);
        bf16v8 bh1 = *(const bf16v8*)(smem + rb + p1);
        bf16v8 bl0 = *(const bf16v8*)(smem + rb + 1024 + p0);
        bf16v8 bl1 = *(const bf16v8*)(smem + rb + 1024 + p1);
        const float eps = e2s[t2 * 16 + cq];
        f32v4 a = {0.f, 0.f, 0.f, 0.f};
        __builtin_amdgcn_s_setprio(1);
        a = __builtin_amdgcn_mfma_f32_16x16x32_bf16(vahi[0], bh0, a, 0, 0, 0);
        a = __builtin_amdgcn_mfma_f32_16x16x32_bf16(vahi[1], bh1, a, 0, 0, 0);
        a = __builtin_amdgcn_mfma_f32_16x16x32_bf16(vahi[0], bl0, a, 0, 0, 0);
        a = __builtin_amdgcn_mfma_f32_16x16x32_bf16(vahi[1], bl1, a, 0, 0, 0);
        a = __builtin_amdgcn_mfma_f32_16x16x32_bf16(valo[0], bh0, a, 0, 0, 0);
        a = __builtin_amdgcn_mfma_f32_16x16x32_bf16(valo[1], bh1, a, 0, 0, 0);
        __builtin_amdgcn_s_setprio(0);
        const int n = t2 * 16 + cq;
        #pragma unroll
        for (int r = 0; r < 4; ++r) {
            float s = fmaf(-0.5f, eps, a[r]);      // score = dot - e2/2
            bool gt = s > m1[r];
            m2[r] = fminf(fmaxf(s, m2[r]), m1[r]);
            i1[r] = gt ? n : i1[r];
            m1[r] = fmaxf(s, m1[r]);
        }
    }

    // merge top-2 (score domain: prefer larger s; on ties lower index)
    #pragma unroll
    for (int r = 0; r < 4; ++r) {
        #pragma unroll
        for (int off = 1; off <= 8; off <<= 1) {
            float o1 = __shfl_xor(m1[r], off, 64);
            float o2 = __shfl_xor(m2[r], off, 64);
            int   oi = __shfl_xor(i1[r], off, 64);
            if (o1 > m1[r] || (o1 == m1[r] && oi < i1[r])) {
                m2[r] = fmaxf(m1[r], o2); m1[r] = o1; i1[r] = oi;
            } else {
                m2[r] = fmaxf(m2[r], o1);
            }
        }
    }
    if (cq == 0) {
        #pragma unroll
        for (int r = 0; r < 4; ++r) {
            int tok = wvu * 16 + qd * 4 + r;
            dT[tok] = m1[r]; d2T[tok] = m2[r]; iT[tok] = i1[r];
        }
    }
    __syncthreads();

    if (wv == 0) {
        float s1 = dT[lane], s2 = d2T[lane];
        if (s1 - s2 < MARGIN * 0.5f) {             // d2-d1 = 2(s1-s2) < MARGIN
            int pos = atomicAdd(cnt, 1);
            if (pos < CAP) wl[pos] = ((b << 6) + lane) * 64 + h;
        }
        float ms = z2s[lane] - 2.f * s1;
        #pragma unroll
        for (int off = 32; off; off >>= 1) ms += __shfl_xor(ms, off, 64);
        if (lane == 0) atomicAdd(accs + 0, ms);
    }
    __syncthreads();

    float* zrow = zq + ((size_t)(b * 64) << 12) + (h << 6) + lane;
    #pragma unroll
    for (int cc = 0; cc < 16; ++cc) {
        int c = wvu * 16 + cc;
        int id = iT[c];
        zrow[(size_t)c << 12] = emb[(id << 6) + lane];
    }
}

// ============================================================
// K4: fp64 refinement, ONE token per block (blocks 0..2047) + finalize
//     (block 2048; also reduces sv/sm stats partials). (R6 verbatim)
// ============================================================
__global__ __launch_bounds__(256) void refine_fin(
    const float* __restrict__ x,
    const double* __restrict__ Wd,
    const double* __restrict__ bpd,
    const float* __restrict__ emb,
    const float* __restrict__ eft,
    const int* __restrict__ cnt, const int* __restrict__ wl,
    float* __restrict__ zq,
    const float* __restrict__ accs, const float* __restrict__ en,
    const float* __restrict__ sv, const float* __restrict__ sm,
    const float* __restrict__ r, float* __restrict__ out)
{
    const int tid = threadIdx.x, lane = tid & 63, wv = tid >> 6;

    if (blockIdx.x == 2048) {
        if (wv == 0) {
            float hs = 0.f, rs = 0.f, cv = 0.f, tm = 0.f;
            #pragma unroll
            for (int jj = 0; jj < 8; ++jj) {
                int n = (jj << 6) + lane;
                float rv = r[n];
                float d = rv - en[n];
                hs = fmaf(d, d, hs);
                rs += fminf(fmaxf(rv, 0.9f), 1.1f);
                cv += sv[n];
                tm += sm[n];
            }
            #pragma unroll
            for (int off = 32; off; off >>= 1) {
                hs += __shfl_xor(hs, off, 64); rs += __shfl_xor(rs, off, 64);
                cv += __shfl_xor(cv, off, 64); tm += __shfl_xor(tm, off, 64);
            }
            if (lane == 0) {
                float hsw    = hs * (1.f / 512.f);
                float mean_r = rs * (1.f / 512.f);
                float mse    = accs[0] * (1.f / 4194304.f);
                float cbv    = cv * (1.f / 512.f);
                float tmd    = tm * (1.f / 512.f);
                float loss   = 2.f * mse + hsw + (cbv - tmd);
                out[0]       = loss;
                out[4194305] = cbv;
                out[4194306] = tmd;
                out[4194307] = hsw;
                out[4194308] = 0.f;
                out[4194309] = mean_r;
            }
        }
        return;
    }

    int count = cnt[0]; if (count > CAP) count = CAP;
    const int it = blockIdx.x;
    if (it >= count) return;

    __shared__ double zp[4][64];
    __shared__ double zs[64];
    __shared__ double dsh[4];
    __shared__ int    ish[4];

    const int r2 = wl[it];
    const int b = r2 >> 12, c = (r2 >> 6) & 63, h = r2 & 63;

    // z compute: wave wv covers f in [wv*64, wv*64+64), lane = w; 8-way ILP
    {
        const float* xp = x + (((size_t)(b * 256 + wv * 64)) << 12) + (h << 6) + lane;
        const double* wrow = Wd + c * 256 + wv * 64;
        double zc0 = 0.0, zc1 = 0.0, zc2 = 0.0, zc3 = 0.0;
        double zc4 = 0.0, zc5 = 0.0, zc6 = 0.0, zc7 = 0.0;
        #pragma unroll
        for (int f = 0; f < 64; f += 8) {
            float a0 = xp[(size_t)(f + 0) << 12];
            float a1 = xp[(size_t)(f + 1) << 12];
            float a2 = xp[(size_t)(f + 2) << 12];
            float a3 = xp[(size_t)(f + 3) << 12];
            float a4 = xp[(size_t)(f + 4) << 12];
            float a5 = xp[(size_t)(f + 5) << 12];
            float a6 = xp[(size_t)(f + 6) << 12];
            float a7 = xp[(size_t)(f + 7) << 12];
            zc0 = fma(wrow[f + 0], (double)a0, zc0);
            zc1 = fma(wrow[f + 1], (double)a1, zc1);
            zc2 = fma(wrow[f + 2], (double)a2, zc2);
            zc3 = fma(wrow[f + 3], (double)a3, zc3);
            zc4 = fma(wrow[f + 4], (double)a4, zc4);
            zc5 = fma(wrow[f + 5], (double)a5, zc5);
            zc6 = fma(wrow[f + 6], (double)a6, zc6);
            zc7 = fma(wrow[f + 7], (double)a7, zc7);
        }
        zp[wv][lane] = ((zc0 + zc1) + (zc2 + zc3)) + ((zc4 + zc5) + (zc6 + zc7));
    }
    __syncthreads();
    if (tid < 64) zs[tid] = (zp[0][tid] + zp[1][tid]) + (zp[2][tid] + zp[3][tid]) + bpd[c];
    __syncthreads();

    // distances for candidates n0 = tid, n1 = tid+256; 8 fp64 chains
    const int n0 = tid, n1 = tid + 256;
    double d0a = 0.0, d0b = 0.0, d0c = 0.0, d0d = 0.0;
    double d1a = 0.0, d1b = 0.0, d1c = 0.0, d1d = 0.0;
    #pragma unroll 4
    for (int k = 0; k < 64; k += 4) {
        double z0 = zs[k], z1 = zs[k + 1], z2 = zs[k + 2], z3 = zs[k + 3];
        double t;
        t = z0 - (double)eft[((k + 0) << 9) + n0]; d0a = fma(t, t, d0a);
        t = z1 - (double)eft[((k + 1) << 9) + n0]; d0b = fma(t, t, d0b);
        t = z2 - (double)eft[((k + 2) << 9) + n0]; d0c = fma(t, t, d0c);
        t = z3 - (double)eft[((k + 3) << 9) + n0]; d0d = fma(t, t, d0d);
        t = z0 - (double)eft[((k + 0) << 9) + n1]; d1a = fma(t, t, d1a);
        t = z1 - (double)eft[((k + 1) << 9) + n1]; d1b = fma(t, t, d1b);
        t = z2 - (double)eft[((k + 2) << 9) + n1]; d1c = fma(t, t, d1c);
        t = z3 - (double)eft[((k + 3) << 9) + n1]; d1d = fma(t, t, d1d);
    }
    double d0 = (d0a + d0b) + (d0c + d0d);
    double d1 = (d1a + d1b) + (d1c + d1d);
    double dm; int im;
    if (d1 < d0) { dm = d1; im = n1; } else { dm = d0; im = n0; }  // n0 < n1

    // wave shuffle-min (value, index; tie -> lower index)
    #pragma unroll
    for (int off = 32; off; off >>= 1) {
        double od = __shfl_xor(dm, off, 64);
        int    oi = __shfl_xor(im, off, 64);
        if (od < dm || (od == dm && oi < im)) { dm = od; im = oi; }
    }
    if (lane == 0) { dsh[wv] = dm; ish[wv] = im; }
    __syncthreads();

    if (tid < 64) {
        double best = dsh[0]; int bi = ish[0];
        #pragma unroll
        for (int wq = 1; wq < 4; ++wq) {
            double od = dsh[wq]; int oi = ish[wq];
            if (od < best || (od == best && oi < bi)) { best = od; bi = oi; }
        }
        zq[((size_t)r2 << 6) + tid] = emb[(bi << 6) + tid];
    }
}

// ============================================================
extern "C" void kernel_launch(void* const* d_in, const int* in_sizes, int n_in,
                              void* d_out, int out_size, void* d_ws, size_t ws_size,
                              hipStream_t stream) {
    const float* x   = (const float*)d_in[0];
    const float* g1  = (const float*)d_in[1];
    const float* be1 = (const float*)d_in[2];
    const float* w1  = (const float*)d_in[3];
    const float* b1  = (const float*)d_in[4];
    const float* w2  = (const float*)d_in[5];
    const float* b2  = (const float*)d_in[6];
    const float* emb = (const float*)d_in[7];
    const float* r   = (const float*)d_in[8];
    float* ws = (float*)d_ws;
    float* out = (float*)d_out;

    double* WD   = (double*)(ws + WS_WD);
    double* BPD  = (double*)(ws + WS_BPD);
    double* PART = (double*)(ws + WS_PART);
    int*    CNT  = (int*)(ws + WS_CNT);
    int*    WL   = (int*)(ws + WS_WL);
    unsigned short* WHI = (unsigned short*)(ws + WS_WHI);
    unsigned short* WLO = (unsigned short*)(ws + WS_WLO);
    unsigned short* EHI = (unsigned short*)(ws + WS_EHI);
    unsigned short* ELO = (unsigned short*)(ws + WS_ELO);

    bn_stats_prep<<<1600, 256, 0, stream>>>(x, PART, emb,
                                            ws + WS_EFT, ws + WS_EN, ws + WS_E2,
                                            EHI, ELO, ws + WS_SV, ws + WS_SM);
    prep<<<65, 256, 0, stream>>>(w1, w2, b1, b2, g1, be1, PART,
                                 WHI, WLO, WD, BPD, ws + WS_BP,
                                 ws + WS_ACC, CNT);
    fused_gemm_vq<<<1024, 256, 0, stream>>>(x, WHI, WLO, ws + WS_BP,
                                            emb, ws + WS_E2,
                                            EHI, ELO, ws + WS_ACC, CNT, WL, out + 1);
    refine_fin<<<2049, 256, 0, stream>>>(x, WD, BPD, emb, ws + WS_EFT, CNT, WL,
                                         out + 1, ws + WS_ACC, ws + WS_EN,
                                         ws + WS_SV, ws + WS_SM, r, out);
}

// Round 11
// 179.457 us; speedup vs baseline: 1.2263x; 1.0113x over previous
//
#include <hip/hip_runtime.h>
#include <math.h>

// ---------- problem constants ----------
// B=16, F=256, C=64, H=64, W=64, N_E=512. Inputs fp32, outputs fp32.
// tokens: rows r=(b*64+c)*64+h of 64 w-values; 65536 tokens total.
// bf16-split MFMA GEMM + bf16-split MFMA VQ; near-ties re-resolved in fp64.
// FINAL: R9 config (verified 181.5 us) — R6 + VQ loop unroll 2.

#define CAP    2048
#define MARGIN 4e-3f

// ---------- workspace layout (float offsets) ----------
#define WS_WHI  0        // [16384 ushort] W' hi bf16, A-frag order
#define WS_WLO  8192     // [16384 ushort] W' lo bf16
#define WS_BP   16384    // [64]
#define WS_EN   16448    // [512]
#define WS_E2   16960    // [512]
#define WS_ACC  17472    // [8]
#define WS_CNT  17480    // [8]
#define WS_WL   17488    // [2048]
#define WS_EFT  19536    // [64*512] fp32 emb^T
#define WS_WD   52304    // [16384 dbl]
#define WS_BPD  85072    // [64 dbl]
#define WS_EHI  85200    // [32768 ushort] emb hi bf16, XOR-swizzled granules
#define WS_ELO  101584   // [32768 ushort] emb lo bf16, swizzled
#define WS_PART 117968   // [2048 dbl] bn partials (1024 blocks x {s,q})
#define WS_SV   122064   // [512] cb-stats per-row variance partials
#define WS_SM   122576   // [512] cb-stats per-row 2nd-min partials

typedef __attribute__((ext_vector_type(8))) __bf16 bf16v8;
typedef __attribute__((ext_vector_type(2))) __bf16 bf16v2;
typedef __attribute__((ext_vector_type(4))) float  f32v4;
typedef __attribute__((ext_vector_type(4))) unsigned u32v4;

__device__ __forceinline__ unsigned short f2bf(float f) {
    __bf16 h = (__bf16)f;
    return __builtin_bit_cast(unsigned short, h);
}
__device__ __forceinline__ float bf2f(unsigned short h) {
    union { unsigned u; float f; } v; v.u = ((unsigned)h) << 16; return v.f;
}
__device__ __forceinline__ unsigned pack_bf2(float a, float b) {
    bf16v2 v = { (__bf16)a, (__bf16)b };
    return __builtin_bit_cast(unsigned, v);
}
__device__ __forceinline__ float bfhi(float a) {
    return (float)(__bf16)a;
}
__device__ __forceinline__ void load_lds16(const float* g, unsigned* l) {
    __builtin_amdgcn_global_load_lds((const __attribute__((address_space(1))) void*)g,
                                     (__attribute__((address_space(3))) void*)l, 16, 0, 0);
}

// ============================================================
// K1: blocks 0..1023: BN partials (memory-bound). blocks 1024..1087:
//     emb prep. 1088..1599: cb angular stats (VALU, hides under BN).
// ============================================================
__global__ __launch_bounds__(256) void bn_stats_prep(
    const float* __restrict__ x, double* __restrict__ part,
    const float* __restrict__ emb,
    float* __restrict__ eft, float* __restrict__ en, float* __restrict__ e2,
    unsigned short* __restrict__ ehi, unsigned short* __restrict__ elo,
    float* __restrict__ sv, float* __restrict__ sm)
{
    const int t = threadIdx.x;

    if (blockIdx.x < 1024) {
        // ---- BN partial sums ----
        const int f = blockIdx.x >> 2, ch = blockIdx.x & 3;
        double s0 = 0.0, s1 = 0.0, q0 = 0.0, q1 = 0.0, q2 = 0.0, q3 = 0.0;
        #pragma unroll
        for (int bb = 0; bb < 4; ++bb) {
            const int b = ch * 4 + bb;
            const float4* p = (const float4*)(x + ((size_t)(b * 256 + f) << 12));
            #pragma unroll
            for (int ii = 0; ii < 4; ++ii) {
                float4 u = p[t + ii * 256];
                double dx = u.x, dy = u.y, dz = u.z, dw = u.w;
                s0 += dx + dy; s1 += dz + dw;
                q0 = fma(dx, dx, q0); q1 = fma(dy, dy, q1);
                q2 = fma(dz, dz, q2); q3 = fma(dw, dw, q3);
            }
        }
        double s = s0 + s1, q = (q0 + q1) + (q2 + q3);
        #pragma unroll
        for (int off = 32; off; off >>= 1) { s += __shfl_xor(s, off, 64); q += __shfl_xor(q, off, 64); }
        __shared__ double sh[8];
        const int wv = t >> 6;
        if ((t & 63) == 0) { sh[wv * 2] = s; sh[wv * 2 + 1] = q; }
        __syncthreads();
        if (t == 0) {
            part[blockIdx.x * 2]     = (sh[0] + sh[2]) + (sh[4] + sh[6]);
            part[blockIdx.x * 2 + 1] = (sh[1] + sh[3]) + (sh[5] + sh[7]);
        }
    } else if (blockIdx.x < 1088) {
        // ---- embedding prep: 8 rows per block ----
        const int blk = blockIdx.x - 1024;
        const int lane = t & 63, wv = t >> 6;
        #pragma unroll
        for (int rr = 0; rr < 2; ++rr) {
            int n = blk * 8 + rr * 4 + wv;
            float v = emb[n * 64 + lane];
            eft[lane * 512 + n] = v;
            unsigned short hb = f2bf(v);
            unsigned short lb = f2bf(v - bf2f(hb));
            int pos = (lane >> 3) ^ (n & 7);          // XOR-swizzled granule
            ehi[n * 64 + pos * 8 + (lane & 7)] = hb;
            elo[n * 64 + pos * 8 + (lane & 7)] = lb;
            float qq = v * v;
            #pragma unroll
            for (int off = 32; off; off >>= 1) qq += __shfl_xor(qq, off, 64);
            if (lane == 0) { e2[n] = qq; en[n] = sqrtf(qq); }
        }
    } else {
        // ---- codebook angular stats for row i (reads emb directly) ----
        const int i = blockIdx.x - 1088;
        const int lane = t & 63, wv = t >> 6;
        __shared__ float ei_sh[64];
        __shared__ float ang[512];
        if (t < 64) ei_sh[t] = emb[(i << 6) + t];
        __syncthreads();
        float ni0 = 0.f, ni1 = 0.f, ni2 = 0.f, ni3 = 0.f;
        #pragma unroll
        for (int k = 0; k < 64; k += 4) {
            ni0 = fmaf(ei_sh[k + 0], ei_sh[k + 0], ni0);
            ni1 = fmaf(ei_sh[k + 1], ei_sh[k + 1], ni1);
            ni2 = fmaf(ei_sh[k + 2], ei_sh[k + 2], ni2);
            ni3 = fmaf(ei_sh[k + 3], ei_sh[k + 3], ni3);
        }
        const float eni = sqrtf((ni0 + ni1) + (ni2 + ni3));
        #pragma unroll
        for (int jj = 0; jj < 2; ++jj) {
            const int j = t + jj * 256;
            const float4* er = (const float4*)(emb + ((size_t)j << 6));
            float d0 = 0.f, d1 = 0.f, d2 = 0.f, d3 = 0.f;
            float n0 = 0.f, n1 = 0.f, n2 = 0.f, n3 = 0.f;
            #pragma unroll
            for (int k4 = 0; k4 < 16; ++k4) {
                float4 u = er[k4];
                const float* e4 = ei_sh + k4 * 4;
                d0 = fmaf(u.x, e4[0], d0); d1 = fmaf(u.y, e4[1], d1);
                d2 = fmaf(u.z, e4[2], d2); d3 = fmaf(u.w, e4[3], d3);
                n0 = fmaf(u.x, u.x, n0);   n1 = fmaf(u.y, u.y, n1);
                n2 = fmaf(u.z, u.z, n2);   n3 = fmaf(u.w, u.w, n3);
            }
            float dot = (d0 + d1) + (d2 + d3);
            float enj = sqrtf((n0 + n1) + (n2 + n3));
            float xv = dot / (eni * enj);
            xv = fminf(fmaxf(xv, -0.99999f), 0.99999f);
            ang[j] = acosf(xv);
        }
        __syncthreads();
        if (wv == 0) {
            float m1 = 3.4e38f, m2 = 3.4e38f, ssum = 0.f;
            #pragma unroll
            for (int t8 = 0; t8 < 8; ++t8) {
                float a = ang[t8 * 64 + lane];
                ssum += a;
                if (a < m1) { m2 = m1; m1 = a; }
                else if (a < m2) m2 = a;
            }
            #pragma unroll
            for (int off = 32; off; off >>= 1) ssum += __shfl_xor(ssum, off, 64);
            #pragma unroll
            for (int off = 32; off; off >>= 1) {
                float o1 = __shfl_xor(m1, off, 64);
                float o2 = __shfl_xor(m2, off, 64);
                if (o1 < m1) { m2 = fminf(m1, o2); m1 = o1; }
                else          m2 = fminf(m2, o1);
            }
            float mean = ssum * (1.f / 512.f);
            float vs = 0.f;
            #pragma unroll
            for (int t8 = 0; t8 < 8; ++t8) {
                float tt = ang[t8 * 64 + lane] - mean;
                vs = fmaf(tt, tt, vs);
            }
            #pragma unroll
            for (int off = 32; off; off >>= 1) vs += __shfl_xor(vs, off, 64);
            if (lane == 0) { sv[i] = vs * (1.f / 511.f); sm[i] = m2; }
        }
    }
}

// ============================================================
// K2: prep. Blocks 0..63: a_f + W' fold (fp64) + W' bf16 hi/lo A-frag split.
//     Block 64: c_f + bias + zero accs/cnt.
// ============================================================
__global__ __launch_bounds__(256) void prep(
    const float* __restrict__ w1, const float* __restrict__ w2,
    const float* __restrict__ b1, const float* __restrict__ b2,
    const float* __restrict__ gamma, const float* __restrict__ beta,
    const double* __restrict__ part,
    unsigned short* __restrict__ whi, unsigned short* __restrict__ wlo,
    double* __restrict__ Wd,
    double* __restrict__ bpd, float* __restrict__ bp,
    float* __restrict__ accs, int* __restrict__ cnt)
{
    __shared__ double sh_ad[4];
    __shared__ double cdl[256];
    __shared__ double red[4][64];
    __shared__ double tsh[64];
    const int t = threadIdx.x;

    if (blockIdx.x < 64) {
        const int o = t & 63, fi = t >> 6;
        const int f = blockIdx.x * 4 + fi;
        if (o == 0) {
            double s = (part[(4 * f) * 2]     + part[(4 * f + 1) * 2])
                     + (part[(4 * f + 2) * 2] + part[(4 * f + 3) * 2]);
            double q = (part[(4 * f) * 2 + 1]     + part[(4 * f + 1) * 2 + 1])
                     + (part[(4 * f + 2) * 2 + 1] + part[(4 * f + 3) * 2 + 1]);
            double mean = s * (1.0 / 65536.0);
            double var  = q * (1.0 / 65536.0) - mean * mean;
            sh_ad[fi] = (double)gamma[f] / sqrt(var + 1e-5);
        }
        __syncthreads();
        double s = 0.0;
        for (int c = 0; c < 64; ++c)
            s = fma((double)w2[o * 64 + c], (double)w1[c * 256 + f], s);
        double wp = s * sh_ad[fi];
        Wd[o * 256 + f] = wp;
        {
            float wpf = (float)wp;
            unsigned short wh = f2bf(wpf);
            unsigned short wlv = f2bf(wpf - bf2f(wh));
            int mt = o >> 4, cq_ = o & 15, sK = f >> 5, qd_ = (f >> 3) & 3, j = f & 7;
            int idx = ((mt * 8 + sK) * 64 + qd_ * 16 + cq_) * 8 + j;
            whi[idx] = wh; wlo[idx] = wlv;
        }
    } else {
        {
            const int f = t;
            double s = (part[(4 * f) * 2]     + part[(4 * f + 1) * 2])
                     + (part[(4 * f + 2) * 2] + part[(4 * f + 3) * 2]);
            double q = (part[(4 * f) * 2 + 1]     + part[(4 * f + 1) * 2 + 1])
                     + (part[(4 * f + 2) * 2 + 1] + part[(4 * f + 3) * 2 + 1]);
            double mean = s * (1.0 / 65536.0);
            double var  = q * (1.0 / 65536.0) - mean * mean;
            double a = (double)gamma[f] / sqrt(var + 1e-5);
            cdl[f] = (double)beta[f] - mean * a;
        }
        __syncthreads();
        const int o = t & 63, p = t >> 6;
        double ss = 0.0;
        for (int j = 0; j < 64; ++j) {
            int fidx = p * 64 + j;
            ss = fma((double)w1[o * 256 + fidx], cdl[fidx], ss);
        }
        red[p][o] = ss; __syncthreads();
        if (t < 64) tsh[t] = (double)b1[t] + (red[0][t] + red[1][t]) + (red[2][t] + red[3][t]);
        __syncthreads();
        if (t < 64) {
            double bb = (double)b2[t];
            for (int c = 0; c < 64; ++c)
                bb = fma((double)w2[t * 64 + c], tsh[c], bb);
            bpd[t] = bb;
            bp[t]  = (float)bb;
        }
        if (t < 8) accs[t] = 0.f;
        if (t == 0) cnt[0] = 0;
    }
}

// ============================================================
// K3: 1024 blocks, one (b,h) each: MFMA GEMM + MFMA VQ.
// LB(256,4), XCD swizzle, 2-deep x prefetch, VQ loop unroll 2.
// ============================================================
__global__ __launch_bounds__(256, 4) void fused_gemm_vq(
    const float* __restrict__ x,
    const unsigned short* __restrict__ whi,
    const unsigned short* __restrict__ wlo,
    const float* __restrict__ bp,
    const float* __restrict__ emb,
    const float* __restrict__ e2,
    const unsigned short* __restrict__ ehi,
    const unsigned short* __restrict__ elo,
    float* __restrict__ accs,
    int* __restrict__ cnt, int* __restrict__ wl,
    float* __restrict__ zq)
{
    __shared__ __align__(16) unsigned smem[4880];
    enum { OAR = 0,   // [0,4096): XB hi/lo during GEMM -> z hi/lo -> VQ staging
           OE2 = 4096, OZ2 = 4608, ODT = 4672, OD2T = 4736, OIT = 4800 };
    float* e2s = (float*)(smem + OE2);
    float* z2s = (float*)(smem + OZ2);
    float* dT  = (float*)(smem + ODT);   // top-1 SCORE per token
    float* d2T = (float*)(smem + OD2T);  // top-2 SCORE per token
    int*   iT  = (int*)(smem + OIT);

    const int tid = threadIdx.x, lane = tid & 63, wv = tid >> 6;
    const int wvu = __builtin_amdgcn_readfirstlane(wv);
    const int lb = ((blockIdx.x & 7) << 7) | (blockIdx.x >> 3);   // XCD swizzle
    const int b = lb >> 6, h = lb & 63;
    const int cq = lane & 15, qd = lane >> 4;

    // A-frags (W' hi/lo), coalesced global b128 loads
    bf16v8 Ahi[8], Alo[8];
    #pragma unroll
    for (int s = 0; s < 8; ++s) {
        Ahi[s] = *(const bf16v8*)(whi + ((size_t)((wvu * 8 + s) * 64 + lane)) * 8);
        Alo[s] = *(const bf16v8*)(wlo + ((size_t)((wvu * 8 + s) * 64 + lane)) * 8);
    }
    float bpv[4];
    #pragma unroll
    for (int r = 0; r < 4; ++r) bpv[r] = bp[wvu * 16 + qd * 4 + r];
    e2s[tid]       = e2[tid];
    e2s[tid + 256] = e2[tid + 256];

    const float* xb = x + ((size_t)(b * 256 + wvu * 16) << 12) + (h << 6) + lane;
    float xva[16], xvb[16];
    #pragma unroll
    for (int i = 0; i < 16; ++i) xva[i] = xb[(size_t)i << 12];
    #pragma unroll
    for (int i = 0; i < 16; ++i) xvb[i] = xb[((size_t)(64 + i)) << 12];

    f32v4 acc[4];
    #pragma unroll
    for (int nt = 0; nt < 4; ++nt) acc[nt] = (f32v4){bpv[0], bpv[1], bpv[2], bpv[3]};

    // one GEMM chunk: stage CUR into XB, (reload CUR with chunk CHK+2), MFMAs
#define GEMM_CHUNK(CHK, CUR)                                                          \
    {                                                                                 \
        __syncthreads();                           /* XB free */                      \
        {                                                                             \
            unsigned hb[8], lbv[8];                                                   \
            _Pragma("unroll")                                                         \
            for (int p = 0; p < 8; ++p) {                                             \
                float a = CUR[2 * p], bq = CUR[2 * p + 1];                            \
                hb[p] = pack_bf2(a, bq);                                              \
                lbv[p] = pack_bf2(a - bfhi(a), bq - bfhi(bq));                        \
            }                                                                         \
            const int b0 = lane * 32 + (((2 * wvu) ^ (lane & 7)) << 2);               \
            const int b1_ = lane * 32 + (((2 * wvu + 1) ^ (lane & 7)) << 2);          \
            *(u32v4*)(smem + OAR + b0)         = (u32v4){hb[0], hb[1], hb[2], hb[3]}; \
            *(u32v4*)(smem + OAR + b1_)        = (u32v4){hb[4], hb[5], hb[6], hb[7]}; \
            *(u32v4*)(smem + OAR + 2048 + b0)  = (u32v4){lbv[0], lbv[1], lbv[2], lbv[3]}; \
            *(u32v4*)(smem + OAR + 2048 + b1_) = (u32v4){lbv[4], lbv[5], lbv[6], lbv[7]}; \
        }                                                                             \
        __syncthreads();                           /* XB ready */                     \
        if (CHK < 2) {                             /* reload CUR with chunk CHK+2 */  \
            const float* xb2 = xb + ((size_t)((CHK + 2) * 64) << 12);                 \
            _Pragma("unroll")                                                         \
            for (int i = 0; i < 16; ++i) CUR[i] = xb2[(size_t)i << 12];               \
        }                                                                             \
        _Pragma("unroll")                                                             \
        for (int st2 = 0; st2 < 2; ++st2) {                                           \
            const int s = CHK * 2 + st2;                                              \
            _Pragma("unroll")                                                         \
            for (int nt = 0; nt < 4; ++nt) {                                          \
                const int row = nt * 16 + cq;                                         \
                const int pos = row * 32 + (((st2 * 4 + qd) ^ (row & 7)) << 2);       \
                bf16v8 bh = *(const bf16v8*)(smem + OAR + pos);                       \
                bf16v8 bl = *(const bf16v8*)(smem + OAR + 2048 + pos);                \
                acc[nt] = __builtin_amdgcn_mfma_f32_16x16x32_bf16(Ahi[s], bh, acc[nt], 0, 0, 0); \
                acc[nt] = __builtin_amdgcn_mfma_f32_16x16x32_bf16(Ahi[s], bl, acc[nt], 0, 0, 0); \
                acc[nt] = __builtin_amdgcn_mfma_f32_16x16x32_bf16(Alo[s], bh, acc[nt], 0, 0, 0); \
            }                                                                         \
        }                                                                             \
    }

    GEMM_CHUNK(0, xva)
    GEMM_CHUNK(1, xvb)
    GEMM_CHUNK(2, xva)
    GEMM_CHUNK(3, xvb)
#undef GEMM_CHUNK

    __syncthreads();                               // last MFMA reads done

    // z2 + write z hi/lo into arena
    {
        float z2p[4];
        #pragma unroll
        for (int r = 0; r < 4; ++r) {
            float p2 = 0.f;
            #pragma unroll
            for (int nt = 0; nt < 4; ++nt) p2 = fmaf(acc[nt][r], acc[nt][r], p2);
            #pragma unroll
            for (int off = 1; off <= 8; off <<= 1) p2 += __shfl_xor(p2, off, 64);
            z2p[r] = p2;
        }
        if (cq == 0) {
            #pragma unroll
            for (int r = 0; r < 4; ++r) z2s[wvu * 16 + qd * 4 + r] = z2p[r];
        }
        unsigned short* ar = (unsigned short*)(smem + OAR);
        #pragma unroll
        for (int nt = 0; nt < 4; ++nt) {
            const int w = nt * 16 + cq;
            const int gz = w >> 3, kj = w & 7;
            #pragma unroll
            for (int r = 0; r < 4; ++r) {
                const int tok = wvu * 16 + qd * 4 + r;
                const int hw = tok * 64 + ((gz ^ (tok & 7)) << 3) + kj;
                unsigned short zh = f2bf(acc[nt][r]);
                ar[hw]        = zh;
                ar[4096 + hw] = f2bf(acc[nt][r] - bf2f(zh));
            }
        }
    }
    __syncthreads();                               // z arena ready

    const int x7 = cq & 7;
    bf16v8 vahi[2], valo[2];
    {
        const int rbase = (wvu * 16 + cq) * 32;
        #pragma unroll
        for (int s = 0; s < 2; ++s) {
            int pos = ((s * 4 + qd) ^ x7) * 4;
            vahi[s] = *(const bf16v8*)(smem + OAR + rbase + pos);
            valo[s] = *(const bf16v8*)(smem + OAR + 2048 + rbase + pos);
        }
    }
    __syncthreads();                               // arena becomes staging

    // stage code tiles 0,1 — distributed across waves
    {
        const float* gh = (const float*)ehi;
        const float* gl = (const float*)elo;
        load_lds16(gh + wvu * 256 + lane * 4,        smem + OAR + wvu * 256);
        load_lds16(gl + wvu * 256 + lane * 4,        smem + OAR + 1024 + wvu * 256);
        load_lds16(gh + 1024 + wvu * 256 + lane * 4, smem + OAR + 2048 + wvu * 256);
        load_lds16(gl + 1024 + wvu * 256 + lane * 4, smem + OAR + 3072 + wvu * 256);
    }

    float m1[4] = {-3.4e38f, -3.4e38f, -3.4e38f, -3.4e38f};
    float m2[4] = {-3.4e38f, -3.4e38f, -3.4e38f, -3.4e38f};
    int   i1[4] = {0, 0, 0, 0};
    const int p0 = (qd ^ x7) * 4, p1 = ((4 + qd) ^ x7) * 4;

    #pragma unroll 2
    for (int t2 = 0; t2 < 32; ++t2) {
        if ((t2 & 1) == 0) {
            __syncthreads();                       // staged tile (t2>>1) ready
            int st = t2 >> 1;
            if (st >= 1 && st < 15) {
                const float* gh = (const float*)ehi + (size_t)(st + 1) * 1024;
                const float* gl = (const float*)elo + (size_t)(st + 1) * 1024;
                unsigned* dst = smem + OAR + ((st + 1) & 1) * 2048;
                load_lds16(gh + wvu * 256 + lane * 4, dst + wvu * 256);
                load_lds16(gl + wvu * 256 + lane * 4, dst + 1024 + wvu * 256);
            }
        }
        const int rb = OAR + ((t2 >> 1) & 1) * 2048 + ((t2 & 1) * 16 + cq) * 32;
        bf16v8 bh0 = *(const bf16v8*)(smem + rb + p0);
        bf16v8 bh1 = *(const bf16v8*)(smem + rb + p1);
        bf16v8 bl0 = *(const bf16v8*)(smem + rb + 1024 + p0);
        bf16v8 bl1 = *(const bf16v8*)(smem + rb + 1024 + p1);
        const float eps = e2s[t2 * 16 + cq];
        f32v4 a = {0.f, 0.f, 0.f, 0.f};
        __builtin_amdgcn_s_setprio(1);
        a = __builtin_amdgcn_mfma_f32_16x16x32_bf16(vahi[0], bh0, a, 0, 0, 0);
        a = __builtin_amdgcn_mfma_f32_16x16x32_bf16(vahi[1], bh1, a, 0, 0, 0);
        a = __builtin_amdgcn_mfma_f32_16x16x32_bf16(vahi[0], bl0, a, 0, 0, 0);
        a = __builtin_amdgcn_mfma_f32_16x16x32_bf16(vahi[1], bl1, a, 0, 0, 0);
        a = __builtin_amdgcn_mfma_f32_16x16x32_bf16(valo[0], bh0, a, 0, 0, 0);
        a = __builtin_amdgcn_mfma_f32_16x16x32_bf16(valo[1], bh1, a, 0, 0, 0);
        __builtin_amdgcn_s_setprio(0);
        const int n = t2 * 16 + cq;
        #pragma unroll
        for (int r = 0; r < 4; ++r) {
            float s = fmaf(-0.5f, eps, a[r]);      // score = dot - e2/2
            bool gt = s > m1[r];
            m2[r] = fminf(fmaxf(s, m2[r]), m1[r]);
            i1[r] = gt ? n : i1[r];
            m1[r] = fmaxf(s, m1[r]);
        }
    }

    // merge top-2 (score domain: prefer larger s; on ties lower index)
    #pragma unroll
    for (int r = 0; r < 4; ++r) {
        #pragma unroll
        for (int off = 1; off <= 8; off <<= 1) {
            float o1 = __shfl_xor(m1[r], off, 64);
            float o2 = __shfl_xor(m2[r], off, 64);
            int   oi = __shfl_xor(i1[r], off, 64);
            if (o1 > m1[r] || (o1 == m1[r] && oi < i1[r])) {
                m2[r] = fmaxf(m1[r], o2); m1[r] = o1; i1[r] = oi;
            } else {
                m2[r] = fmaxf(m2[r], o1);
            }
        }
    }
    if (cq == 0) {
        #pragma unroll
        for (int r = 0; r < 4; ++r) {
            int tok = wvu * 16 + qd * 4 + r;
            dT[tok] = m1[r]; d2T[tok] = m2[r]; iT[tok] = i1[r];
        }
    }
    __syncthreads();

    if (wv == 0) {
        float s1 = dT[lane], s2 = d2T[lane];
        if (s1 - s2 < MARGIN * 0.5f) {             // d2-d1 = 2(s1-s2) < MARGIN
            int pos = atomicAdd(cnt, 1);
            if (pos < CAP) wl[pos] = ((b << 6) + lane) * 64 + h;
        }
        float ms = z2s[lane] - 2.f * s1;
        #pragma unroll
        for (int off = 32; off; off >>= 1) ms += __shfl_xor(ms, off, 64);
        if (lane == 0) atomicAdd(accs + 0, ms);
    }
    __syncthreads();

    float* zrow = zq + ((size_t)(b * 64) << 12) + (h << 6) + lane;
    #pragma unroll
    for (int cc = 0; cc < 16; ++cc) {
        int c = wvu * 16 + cc;
        int id = iT[c];
        zrow[(size_t)c << 12] = emb[(id << 6) + lane];
    }
}

// ============================================================
// K4: fp64 refinement, ONE token per block (blocks 0..2047) + finalize
//     (block 2048; also reduces sv/sm stats partials).
// ============================================================
__global__ __launch_bounds__(256) void refine_fin(
    const float* __restrict__ x,
    const double* __restrict__ Wd,
    const double* __restrict__ bpd,
    const float* __restrict__ emb,
    const float* __restrict__ eft,
    const int* __restrict__ cnt, const int* __restrict__ wl,
    float* __restrict__ zq,
    const float* __restrict__ accs, const float* __restrict__ en,
    const float* __restrict__ sv, const float* __restrict__ sm,
    const float* __restrict__ r, float* __restrict__ out)
{
    const int tid = threadIdx.x, lane = tid & 63, wv = tid >> 6;

    if (blockIdx.x == 2048) {
        if (wv == 0) {
            float hs = 0.f, rs = 0.f, cv = 0.f, tm = 0.f;
            #pragma unroll
            for (int jj = 0; jj < 8; ++jj) {
                int n = (jj << 6) + lane;
                float rv = r[n];
                float d = rv - en[n];
                hs = fmaf(d, d, hs);
                rs += fminf(fmaxf(rv, 0.9f), 1.1f);
                cv += sv[n];
                tm += sm[n];
            }
            #pragma unroll
            for (int off = 32; off; off >>= 1) {
                hs += __shfl_xor(hs, off, 64); rs += __shfl_xor(rs, off, 64);
                cv += __shfl_xor(cv, off, 64); tm += __shfl_xor(tm, off, 64);
            }
            if (lane == 0) {
                float hsw    = hs * (1.f / 512.f);
                float mean_r = rs * (1.f / 512.f);
                float mse    = accs[0] * (1.f / 4194304.f);
                float cbv    = cv * (1.f / 512.f);
                float tmd    = tm * (1.f / 512.f);
                float loss   = 2.f * mse + hsw + (cbv - tmd);
                out[0]       = loss;
                out[4194305] = cbv;
                out[4194306] = tmd;
                out[4194307] = hsw;
                out[4194308] = 0.f;
                out[4194309] = mean_r;
            }
        }
        return;
    }

    int count = cnt[0]; if (count > CAP) count = CAP;
    const int it = blockIdx.x;
    if (it >= count) return;

    __shared__ double zp[4][64];
    __shared__ double zs[64];
    __shared__ double dsh[4];
    __shared__ int    ish[4];

    const int r2 = wl[it];
    const int b = r2 >> 12, c = (r2 >> 6) & 63, h = r2 & 63;

    // z compute: wave wv covers f in [wv*64, wv*64+64), lane = w; 8-way ILP
    {
        const float* xp = x + (((size_t)(b * 256 + wv * 64)) << 12) + (h << 6) + lane;
        const double* wrow = Wd + c * 256 + wv * 64;
        double zc0 = 0.0, zc1 = 0.0, zc2 = 0.0, zc3 = 0.0;
        double zc4 = 0.0, zc5 = 0.0, zc6 = 0.0, zc7 = 0.0;
        #pragma unroll
        for (int f = 0; f < 64; f += 8) {
            float a0 = xp[(size_t)(f + 0) << 12];
            float a1 = xp[(size_t)(f + 1) << 12];
            float a2 = xp[(size_t)(f + 2) << 12];
            float a3 = xp[(size_t)(f + 3) << 12];
            float a4 = xp[(size_t)(f + 4) << 12];
            float a5 = xp[(size_t)(f + 5) << 12];
            float a6 = xp[(size_t)(f + 6) << 12];
            float a7 = xp[(size_t)(f + 7) << 12];
            zc0 = fma(wrow[f + 0], (double)a0, zc0);
            zc1 = fma(wrow[f + 1], (double)a1, zc1);
            zc2 = fma(wrow[f + 2], (double)a2, zc2);
            zc3 = fma(wrow[f + 3], (double)a3, zc3);
            zc4 = fma(wrow[f + 4], (double)a4, zc4);
            zc5 = fma(wrow[f + 5], (double)a5, zc5);
            zc6 = fma(wrow[f + 6], (double)a6, zc6);
            zc7 = fma(wrow[f + 7], (double)a7, zc7);
        }
        zp[wv][lane] = ((zc0 + zc1) + (zc2 + zc3)) + ((zc4 + zc5) + (zc6 + zc7));
    }
    __syncthreads();
    if (tid < 64) zs[tid] = (zp[0][tid] + zp[1][tid]) + (zp[2][tid] + zp[3][tid]) + bpd[c];
    __syncthreads();

    // distances for candidates n0 = tid, n1 = tid+256; 8 fp64 chains
    const int n0 = tid, n1 = tid + 256;
    double d0a = 0.0, d0b = 0.0, d0c = 0.0, d0d = 0.0;
    double d1a = 0.0, d1b = 0.0, d1c = 0.0, d1d = 0.0;
    #pragma unroll 4
    for (int k = 0; k < 64; k += 4) {
        double z0 = zs[k], z1 = zs[k + 1], z2 = zs[k + 2], z3 = zs[k + 3];
        double t;
        t = z0 - (double)eft[((k + 0) << 9) + n0]; d0a = fma(t, t, d0a);
        t = z1 - (double)eft[((k + 1) << 9) + n0]; d0b = fma(t, t, d0b);
        t = z2 - (double)eft[((k + 2) << 9) + n0]; d0c = fma(t, t, d0c);
        t = z3 - (double)eft[((k + 3) << 9) + n0]; d0d = fma(t, t, d0d);
        t = z0 - (double)eft[((k + 0) << 9) + n1]; d1a = fma(t, t, d1a);
        t = z1 - (double)eft[((k + 1) << 9) + n1]; d1b = fma(t, t, d1b);
        t = z2 - (double)eft[((k + 2) << 9) + n1]; d1c = fma(t, t, d1c);
        t = z3 - (double)eft[((k + 3) << 9) + n1]; d1d = fma(t, t, d1d);
    }
    double d0 = (d0a + d0b) + (d0c + d0d);
    double d1 = (d1a + d1b) + (d1c + d1d);
    double dm; int im;
    if (d1 < d0) { dm = d1; im = n1; } else { dm = d0; im = n0; }  // n0 < n1

    // wave shuffle-min (value, index; tie -> lower index)
    #pragma unroll
    for (int off = 32; off; off >>= 1) {
        double od = __shfl_xor(dm, off, 64);
        int    oi = __shfl_xor(im, off, 64);
        if (od < dm || (od == dm && oi < im)) { dm = od; im = oi; }
    }
    if (lane == 0) { dsh[wv] = dm; ish[wv] = im; }
    __syncthreads();

    if (tid < 64) {
        double best = dsh[0]; int bi = ish[0];
        #pragma unroll
        for (int wq = 1; wq < 4; ++wq) {
            double od = dsh[wq]; int oi = ish[wq];
            if (od < best || (od == best && oi < bi)) { best = od; bi = oi; }
        }
        zq[((size_t)r2 << 6) + tid] = emb[(bi << 6) + tid];
    }
}

// ============================================================
extern "C" void kernel_launch(void* const* d_in, const int* in_sizes, int n_in,
                              void* d_out, int out_size, void* d_ws, size_t ws_size,
                              hipStream_t stream) {
    const float* x   = (const float*)d_in[0];
    const float* g1  = (const float*)d_in[1];
    const float* be1 = (const float*)d_in[2];
    const float* w1  = (const float*)d_in[3];
    const float* b1  = (const float*)d_in[4];
    const float* w2  = (const float*)d_in[5];
    const float* b2  = (const float*)d_in[6];
    const float* emb = (const float*)d_in[7];
    const float* r   = (const float*)d_in[8];
    float* ws = (float*)d_ws;
    float* out = (float*)d_out;

    double* WD   = (double*)(ws + WS_WD);
    double* BPD  = (double*)(ws + WS_BPD);
    double* PART = (double*)(ws + WS_PART);
    int*    CNT  = (int*)(ws + WS_CNT);
    int*    WL   = (int*)(ws + WS_WL);
    unsigned short* WHI = (unsigned short*)(ws + WS_WHI);
    unsigned short* WLO = (unsigned short*)(ws + WS_WLO);
    unsigned short* EHI = (unsigned short*)(ws + WS_EHI);
    unsigned short* ELO = (unsigned short*)(ws + WS_ELO);

    bn_stats_prep<<<1600, 256, 0, stream>>>(x, PART, emb,
                                            ws + WS_EFT, ws + WS_EN, ws + WS_E2,
                                            EHI, ELO, ws + WS_SV, ws + WS_SM);
    prep<<<65, 256, 0, stream>>>(w1, w2, b1, b2, g1, be1, PART,
                                 WHI, WLO, WD, BPD, ws + WS_BP,
                                 ws + WS_ACC, CNT);
    fused_gemm_vq<<<1024, 256, 0, stream>>>(x, WHI, WLO, ws + WS_BP,
                                            emb, ws + WS_E2,
                                            EHI, ELO, ws + WS_ACC, CNT, WL, out + 1);
    refine_fin<<<2049, 256, 0, stream>>>(x, WD, BPD, emb, ws + WS_EFT, CNT, WL,
                                         out + 1, ws + WS_ACC, ws + WS_EN,
                                         ws + WS_SV, ws + WS_SM, r, out);
}